// Round 1
// baseline (655.313 us; speedup 1.0000x reference)
//
#include <hip/hip_runtime.h>

// Model constants
#define B0q 8
#define C0q 32
#define Tq 512
#define PREDq 192
#define PLq 16
#define Mq 8
#define ELq 2
#define Sq 32
#define Rq 8
#define DINq 128
#define Pq 32
#define BCq 256     // B0*C0
#define NRq 8192    // BC*P

// ---------------- init: twiddle tables ----------------
__global__ void k_init(float* __restrict__ tw, float* __restrict__ ct, float* __restrict__ st) {
    int idx = blockIdx.x * 256 + threadIdx.x;
    if (idx < 8192) {
        int d = idx >> 6, n = idx & 63;
        int x = n >> 1, c = n & 1;
        float ang = (float)((x * d) & 127) * 0.04908738521234052f; // 2*pi/128
        tw[idx] = (c == 0) ? cosf(ang) : -sinf(ang);
    }
    if (idx < 128) {
        float ang = (float)idx * 0.04908738521234052f;
        ct[idx] = cosf(ang);
        st[idx] = sinf(ang);
    }
}

// ---------------- per-(b,c) mean/std over T ----------------
__global__ void k_stats(const float* __restrict__ x, float* __restrict__ means, float* __restrict__ stdev) {
    int bc = blockIdx.x;
    int b = bc >> 5, c = bc & 31;
    int t = threadIdx.x; // 256
    float s1 = 0.f, s2 = 0.f;
    for (int tt = t; tt < Tq; tt += 256) {
        float v = x[(b * Tq + tt) * C0q + c];
        s1 += v; s2 += v * v;
    }
    #pragma unroll
    for (int off = 32; off > 0; off >>= 1) {
        s1 += __shfl_xor(s1, off);
        s2 += __shfl_xor(s2, off);
    }
    __shared__ float r1[4], r2[4];
    int wave = t >> 6, lane = t & 63;
    if (lane == 0) { r1[wave] = s1; r2[wave] = s2; }
    __syncthreads();
    if (t == 0) {
        float S1 = r1[0] + r1[1] + r1[2] + r1[3];
        float S2 = r2[0] + r2[1] + r2[2] + r2[3];
        float mu = S1 * (1.f / (float)Tq);
        float var = S2 * (1.f / (float)Tq) - mu * mu;
        means[bc] = mu;
        stdev[bc] = sqrtf(var + 1e-5f);
    }
}

// ---------------- PSR embedding ----------------
__global__ void k_embed(const float* __restrict__ x, const float* __restrict__ means,
                        const float* __restrict__ stdev, float* __restrict__ enc,
                        float* __restrict__ encT) {
    int idx = blockIdx.x * 256 + threadIdx.x; // < 1048576
    int bc = idx >> 12, rem = idx & 4095;
    int p = rem >> 7, dd = rem & 127;
    int m = dd >> 4, l = dd & 15;
    int b = bc >> 5, c = bc & 31;
    int t = p * PLq + l;
    float v = 0.f;
    if (t >= 7) v = (x[(b * Tq + (t - 7 + m)) * C0q + c] - means[bc]) / stdev[bc];
    enc[idx] = v;                               // [r=(bc*32+p)][d]
    encT[(dd * 32 + p) * 256 + bc] = v;         // [d][p][bc]
}

// ---------------- LayerNorm + projections ----------------
__global__ void k_lnproj(const float* __restrict__ enc,
                         const float* __restrict__ xw,   // (72,128)
                         const float* __restrict__ dw,   // (128,8)
                         const float* __restrict__ db,   // (128)
                         const float* __restrict__ g, const float* __restrict__ bb,
                         float* __restrict__ xnT,        // [d][p][bc]
                         float* __restrict__ deltaT,     // [p][d][bc]
                         float* __restrict__ BmT,        // [p][s][bc]
                         float* __restrict__ CmT) {      // [o][p][bc]
    int r = blockIdx.x;          // bc*32+p
    int bc = r >> 5, p = r & 31;
    int t = threadIdx.x;         // 128
    __shared__ float xs[128];
    __shared__ float red[4];
    __shared__ float dr[8];
    float e = enc[r * 128 + t];
    float s1 = e, s2 = e * e;
    #pragma unroll
    for (int off = 32; off > 0; off >>= 1) {
        s1 += __shfl_xor(s1, off);
        s2 += __shfl_xor(s2, off);
    }
    if ((t & 63) == 0) { red[(t >> 6) * 2] = s1; red[(t >> 6) * 2 + 1] = s2; }
    __syncthreads();
    float mu = (red[0] + red[2]) * (1.f / 128.f);
    float var = (red[1] + red[3]) * (1.f / 128.f) - mu * mu;
    float inv = rsqrtf(var + 1e-5f);
    float v = (e - mu) * inv * g[t] + bb[t];
    xs[t] = v;
    xnT[(t * 32 + p) * 256 + bc] = v;
    __syncthreads();
    if (t < 72) {
        float acc = 0.f;
        const float* w = xw + t * 128;
        #pragma unroll 8
        for (int d = 0; d < 128; d++) acc += xs[d] * w[d];
        if (t < 8) dr[t] = acc;
        else if (t < 40) BmT[(p * 32 + (t - 8)) * 256 + bc] = acc;
        else CmT[(t - 40) * 8192 + p * 256 + bc] = acc;
    }
    __syncthreads();
    float a = db[t];
    const float* wd = dw + t * 8;
    #pragma unroll
    for (int rr = 0; rr < 8; rr++) a += dr[rr] * wd[rr];
    float sp = fmaxf(a, 0.f) + log1pf(expf(-fabsf(a)));  // stable softplus
    deltaT[(p * 128 + t) * 256 + bc] = sp;
}

// ---------------- selective scan (sequential over P=32) ----------------
__global__ void k_scan(const float* __restrict__ deltaT, const float* __restrict__ xnT,
                       const float* __restrict__ BmT, const float* __restrict__ Alog,
                       float* __restrict__ hsT) {       // [d][s][p][bc]
    int ds = blockIdx.x;       // d*32+s
    int d = ds >> 5;
    int s = ds & 31;
    int bc = threadIdx.x;      // 256
    float A = -expf(Alog[ds]);
    float h = 0.f;
    for (int p = 0; p < 32; p++) {
        float dl = deltaT[(p * 128 + d) * 256 + bc];
        float xv = xnT[(d * 32 + p) * 256 + bc];
        float bv = BmT[(p * 32 + s) * 256 + bc];
        h = expf(dl * A) * h + dl * xv * bv;
        hsT[(ds * 32 + p) * 256 + bc] = h;
    }
    (void)s;
}

// ---------------- forward DFT (32 modes), batched over lanes ----------------
__global__ __launch_bounds__(256) void k_dft(const float* __restrict__ hsT,
                                             const float* __restrict__ tw,   // [128][64]
                                             float* __restrict__ xf) {       // [(x*2+c)*32+i][rp]
    int i = blockIdx.x >> 5;
    int rp = (blockIdx.x & 31) * 256 + threadIdx.x;
    float acc[64];
    #pragma unroll
    for (int n = 0; n < 64; n++) acc[n] = 0.f;
    for (int d = 0; d < 128; d++) {
        float h = hsT[(d * 32 + i) * 8192 + rp];
        const float* twd = tw + d * 64;     // wave-uniform -> scalar loads
        #pragma unroll
        for (int n = 0; n < 64; n++) acc[n] += h * twd[n];
    }
    #pragma unroll
    for (int n = 0; n < 64; n++) xf[(n * 32 + i) * 8192 + rp] = acc[n];
}

// ---------------- mode mixing folded with Cm contraction ----------------
__global__ __launch_bounds__(256) void k_mix(const float* __restrict__ xf,
                                             const float* __restrict__ CmT,
                                             const float* __restrict__ Kr,
                                             const float* __restrict__ Ki,
                                             float* __restrict__ gbuf) {     // [x*2+c][rp]
    int x = blockIdx.x >> 5;
    int rp = (blockIdx.x & 31) * 256 + threadIdx.x;
    float cm[32];
    #pragma unroll
    for (int o = 0; o < 32; o++) cm[o] = CmT[o * 8192 + rp];
    float gr = 0.f, gi = 0.f;
    for (int i = 0; i < 32; i++) {
        float wcr = 0.f, wci = 0.f;
        #pragma unroll
        for (int o = 0; o < 32; o++) {
            wcr += Kr[(i * 32 + o) * 32 + x] * cm[o];   // wave-uniform weights
            wci += Ki[(i * 32 + o) * 32 + x] * cm[o];
        }
        float xr = xf[((x * 2 + 0) * 32 + i) * 8192 + rp];
        float xi = xf[((x * 2 + 1) * 32 + i) * 8192 + rp];
        gr += xr * wcr - xi * wci;
        gi += xr * wci + xi * wcr;
    }
    gbuf[(x * 2 + 0) * 8192 + rp] = gr;
    gbuf[(x * 2 + 1) * 8192 + rp] = gi;
}

// ---------------- irfft + D-skip + residual ----------------
__global__ __launch_bounds__(256) void k_inv(const float* __restrict__ gbuf,
                                             const float* __restrict__ ct,
                                             const float* __restrict__ st,
                                             const float* __restrict__ Dp,
                                             const float* __restrict__ xnT,
                                             float* __restrict__ encT,
                                             float* __restrict__ enc) {
    int d = blockIdx.x >> 5;
    int rp = (blockIdx.x & 31) * 256 + threadIdx.x;
    float acc = gbuf[rp];   // Re(g[0]); imag of DC dropped (C2R convention)
    for (int x = 1; x < 32; x++) {
        int k = (x * d) & 127;            // wave-uniform
        float c = ct[k], s = st[k];
        acc += 2.f * (gbuf[(x * 2) * 8192 + rp] * c - gbuf[(x * 2 + 1) * 8192 + rp] * s);
    }
    float ys = acc * (1.f / 128.f);
    float v = ys + Dp[d] * xnT[d * 8192 + rp] + encT[d * 8192 + rp];
    encT[d * 8192 + rp] = v;
    int bc = rp & 255, p = rp >> 8;
    enc[(bc * 32 + p) * 128 + d] = v;
}

// ---------------- output head + de-normalization ----------------
__global__ __launch_bounds__(192) void k_final(const float* __restrict__ enc,
                                               const float* __restrict__ ow,  // (192,4096)
                                               const float* __restrict__ ob,
                                               const float* __restrict__ stdev,
                                               const float* __restrict__ means,
                                               float* __restrict__ out) {
    int bc = blockIdx.x;
    int b = bc >> 5, c = bc & 31;
    int t = threadIdx.x;  // 192
    __shared__ float es[4096];
    for (int k = t; k < 4096; k += 192) es[k] = enc[bc * 4096 + k];
    __syncthreads();
    float acc = ob[t];
    const float* w = ow + t * 4096;
    #pragma unroll 8
    for (int k = 0; k < 4096; k++) acc += es[k] * w[k];
    out[(b * PREDq + t) * C0q + c] = acc * stdev[bc] + means[bc];
}

extern "C" void kernel_launch(void* const* d_in, const int* in_sizes, int n_in,
                              void* d_out, int out_size, void* d_ws, size_t ws_size,
                              hipStream_t stream) {
    const float* x     = (const float*)d_in[0];
    const float* xproj = (const float*)d_in[4];
    const float* dtw   = (const float*)d_in[5];
    const float* dtb   = (const float*)d_in[6];
    const float* Alog  = (const float*)d_in[7];
    const float* Dp    = (const float*)d_in[8];
    const float* Kr    = (const float*)d_in[9];
    const float* Ki    = (const float*)d_in[10];
    const float* lng   = (const float*)d_in[11];
    const float* lnb   = (const float*)d_in[12];
    const float* ow    = (const float*)d_in[13];
    const float* ob    = (const float*)d_in[14];
    float* out = (float*)d_out;

    float* w = (float*)d_ws;
    float* means  = w; w += 256;
    float* stdev  = w; w += 256;
    float* tw     = w; w += 8192;
    float* ct     = w; w += 128;
    float* st     = w; w += 128;
    float* enc    = w; w += 1048576;   // [r][d]
    float* encT   = w; w += 1048576;   // [d][p][bc]
    float* xnT    = w; w += 1048576;   // [d][p][bc]
    float* deltaT = w; w += 1048576;   // [p][d][bc]
    float* BmT    = w; w += 262144;    // [p][s][bc]
    float* CmT    = w; w += 262144;    // [o][p][bc]
    float* gbuf   = w; w += 524288;    // [x*2+c][rp]
    float* xfb    = w; w += 16777216;  // [(x*2+c)*32+i][rp]
    float* hsT    = w; w += 33554432;  // [d][s][p][bc]
    // total ~225 MB of ws

    k_init<<<33, 256, 0, stream>>>(tw, ct, st);
    k_stats<<<256, 256, 0, stream>>>(x, means, stdev);
    k_embed<<<4096, 256, 0, stream>>>(x, means, stdev, enc, encT);
    for (int li = 0; li < ELq; li++) {
        k_lnproj<<<8192, 128, 0, stream>>>(enc, xproj + li * 9216, dtw + li * 1024,
                                           dtb + li * 128, lng + li * 128, lnb + li * 128,
                                           xnT, deltaT, BmT, CmT);
        k_scan<<<4096, 256, 0, stream>>>(deltaT, xnT, BmT, Alog + li * 4096, hsT);
        k_dft<<<1024, 256, 0, stream>>>(hsT, tw, xfb);
        k_mix<<<1024, 256, 0, stream>>>(xfb, CmT, Kr + li * 32768, Ki + li * 32768, gbuf);
        k_inv<<<4096, 256, 0, stream>>>(gbuf, ct, st, Dp + li * 128, xnT, encT, enc);
    }
    k_final<<<256, 192, 0, stream>>>(enc, ow, ob, stdev, means, out);
}

// Round 2
// 576.257 us; speedup vs baseline: 1.1372x; 1.1372x over previous
//
#include <hip/hip_runtime.h>

// Model constants
#define B0q 8
#define C0q 32
#define Tq 512
#define PREDq 192
#define PLq 16
#define Mq 8
#define ELq 2
#define Sq 32
#define Rq 8
#define DINq 128
#define Pq 32
#define BCq 256     // B0*C0
#define NRq 8192    // BC*P

// ---------------- init: twiddle tables ----------------
__global__ void k_init(float* __restrict__ tw, float* __restrict__ ct, float* __restrict__ st) {
    int idx = blockIdx.x * 256 + threadIdx.x;
    if (idx < 8192) {
        int d = idx >> 6, n = idx & 63;
        int x = n >> 1, c = n & 1;
        float ang = (float)((x * d) & 127) * 0.04908738521234052f; // 2*pi/128
        tw[idx] = (c == 0) ? cosf(ang) : -sinf(ang);
    }
    if (idx < 128) {
        float ang = (float)idx * 0.04908738521234052f;
        ct[idx] = cosf(ang);
        st[idx] = sinf(ang);
    }
}

// ---------------- per-(b,c) mean/std over T ----------------
__global__ void k_stats(const float* __restrict__ x, float* __restrict__ means, float* __restrict__ stdev) {
    int bc = blockIdx.x;
    int b = bc >> 5, c = bc & 31;
    int t = threadIdx.x; // 256
    float s1 = 0.f, s2 = 0.f;
    for (int tt = t; tt < Tq; tt += 256) {
        float v = x[(b * Tq + tt) * C0q + c];
        s1 += v; s2 += v * v;
    }
    #pragma unroll
    for (int off = 32; off > 0; off >>= 1) {
        s1 += __shfl_xor(s1, off);
        s2 += __shfl_xor(s2, off);
    }
    __shared__ float r1[4], r2[4];
    int wave = t >> 6, lane = t & 63;
    if (lane == 0) { r1[wave] = s1; r2[wave] = s2; }
    __syncthreads();
    if (t == 0) {
        float S1 = r1[0] + r1[1] + r1[2] + r1[3];
        float S2 = r2[0] + r2[1] + r2[2] + r2[3];
        float mu = S1 * (1.f / (float)Tq);
        float var = S2 * (1.f / (float)Tq) - mu * mu;
        means[bc] = mu;
        stdev[bc] = sqrtf(var + 1e-5f);
    }
}

// ---------------- PSR embedding ----------------
__global__ void k_embed(const float* __restrict__ x, const float* __restrict__ means,
                        const float* __restrict__ stdev, float* __restrict__ enc,
                        float* __restrict__ encT) {
    int idx = blockIdx.x * 256 + threadIdx.x; // < 1048576
    int bc = idx >> 12, rem = idx & 4095;
    int p = rem >> 7, dd = rem & 127;
    int m = dd >> 4, l = dd & 15;
    int b = bc >> 5, c = bc & 31;
    int t = p * PLq + l;
    float v = 0.f;
    if (t >= 7) v = (x[(b * Tq + (t - 7 + m)) * C0q + c] - means[bc]) / stdev[bc];
    enc[idx] = v;                               // [r=(bc*32+p)][d]
    encT[(dd * 32 + p) * 256 + bc] = v;         // [d][p][bc]
}

// ---------------- LayerNorm + projections ----------------
__global__ void k_lnproj(const float* __restrict__ enc,
                         const float* __restrict__ xw,   // (72,128)
                         const float* __restrict__ dw,   // (128,8)
                         const float* __restrict__ db,   // (128)
                         const float* __restrict__ g, const float* __restrict__ bb,
                         float* __restrict__ xnT,        // [d][p][bc]
                         float* __restrict__ deltaT,     // [p][d][bc]
                         float* __restrict__ BmT,        // [p][s][bc]
                         float* __restrict__ CmT) {      // [o][p][bc]
    int r = blockIdx.x;          // bc*32+p
    int bc = r >> 5, p = r & 31;
    int t = threadIdx.x;         // 128
    __shared__ float xs[128];
    __shared__ float red[4];
    __shared__ float dr[8];
    float e = enc[r * 128 + t];
    float s1 = e, s2 = e * e;
    #pragma unroll
    for (int off = 32; off > 0; off >>= 1) {
        s1 += __shfl_xor(s1, off);
        s2 += __shfl_xor(s2, off);
    }
    if ((t & 63) == 0) { red[(t >> 6) * 2] = s1; red[(t >> 6) * 2 + 1] = s2; }
    __syncthreads();
    float mu = (red[0] + red[2]) * (1.f / 128.f);
    float var = (red[1] + red[3]) * (1.f / 128.f) - mu * mu;
    float inv = rsqrtf(var + 1e-5f);
    float v = (e - mu) * inv * g[t] + bb[t];
    xs[t] = v;
    xnT[(t * 32 + p) * 256 + bc] = v;
    __syncthreads();
    if (t < 72) {
        float acc = 0.f;
        const float* w = xw + t * 128;
        #pragma unroll 8
        for (int d = 0; d < 128; d++) acc += xs[d] * w[d];
        if (t < 8) dr[t] = acc;
        else if (t < 40) BmT[(p * 32 + (t - 8)) * 256 + bc] = acc;
        else CmT[(t - 40) * 8192 + p * 256 + bc] = acc;
    }
    __syncthreads();
    float a = db[t];
    const float* wd = dw + t * 8;
    #pragma unroll
    for (int rr = 0; rr < 8; rr++) a += dr[rr] * wd[rr];
    float sp = fmaxf(a, 0.f) + log1pf(expf(-fabsf(a)));  // stable softplus
    deltaT[(p * 128 + t) * 256 + bc] = sp;
}

// ---------------- selective scan (sequential over P=32) ----------------
__global__ void k_scan(const float* __restrict__ deltaT, const float* __restrict__ xnT,
                       const float* __restrict__ BmT, const float* __restrict__ Alog,
                       float* __restrict__ hsT) {       // [d][s][p][bc]
    int ds = blockIdx.x;       // d*32+s
    int d = ds >> 5;
    int s = ds & 31;
    int bc = threadIdx.x;      // 256
    float A = -expf(Alog[ds]);
    float h = 0.f;
    for (int p = 0; p < 32; p++) {
        float dl = deltaT[(p * 128 + d) * 256 + bc];
        float xv = xnT[(d * 32 + p) * 256 + bc];
        float bv = BmT[(p * 32 + s) * 256 + bc];
        h = expf(dl * A) * h + dl * xv * bv;
        hsT[(ds * 32 + p) * 256 + bc] = h;
    }
    (void)s;
}

// ---------------- forward DFT (32 modes), batched over lanes ----------------
__global__ __launch_bounds__(256) void k_dft(const float* __restrict__ hsT,
                                             const float* __restrict__ tw,   // [128][64]
                                             float* __restrict__ xf) {       // [(x*2+c)*32+i][rp]
    int i = blockIdx.x >> 5;
    int rp = (blockIdx.x & 31) * 256 + threadIdx.x;
    float acc[64];
    #pragma unroll
    for (int n = 0; n < 64; n++) acc[n] = 0.f;
    for (int d = 0; d < 128; d++) {
        float h = hsT[(d * 32 + i) * 8192 + rp];
        const float* twd = tw + d * 64;     // grid-uniform -> scalar loads, K$-resident
        #pragma unroll
        for (int n = 0; n < 64; n++) acc[n] += h * twd[n];
    }
    #pragma unroll
    for (int n = 0; n < 64; n++) xf[(n * 32 + i) * 8192 + rp] = acc[n];
}

// ---------------- mode mixing folded with Cm contraction ----------------
// block = (x, 512-rp chunk); weights staged in LDS; xf tile in registers (2 rp/thread)
__global__ __launch_bounds__(256) void k_mix(const float* __restrict__ xf,
                                             const float* __restrict__ CmT,
                                             const float* __restrict__ Kr,
                                             const float* __restrict__ Ki,
                                             float* __restrict__ gbuf) {     // [x*2+c][rp]
    int x = blockIdx.x >> 4;
    int rp0 = (blockIdx.x & 15) * 512 + threadIdx.x;   // second rp = rp0+256
    __shared__ float lkr[1024], lki[1024];             // [o][i]
    for (int u = threadIdx.x; u < 1024; u += 256) {
        int o = u >> 5, i = u & 31;
        lkr[u] = Kr[(i * 32 + o) * 32 + x];
        lki[u] = Ki[(i * 32 + o) * 32 + x];
    }
    __syncthreads();
    float xr0[32], xi0[32], xr1[32], xi1[32];
    const float* pr = xf + (x * 64) * 8192 + rp0;
    const float* pi = xf + (x * 64 + 32) * 8192 + rp0;
    #pragma unroll
    for (int i = 0; i < 32; i++) {
        xr0[i] = pr[i * 8192];  xr1[i] = pr[i * 8192 + 256];
        xi0[i] = pi[i * 8192];  xi1[i] = pi[i * 8192 + 256];
    }
    float gr0 = 0.f, gi0 = 0.f, gr1 = 0.f, gi1 = 0.f;
    for (int o = 0; o < 32; o++) {
        float tr0 = 0.f, ti0 = 0.f, tr1 = 0.f, ti1 = 0.f;
        const float4* kr4 = (const float4*)(lkr + o * 32);
        const float4* ki4 = (const float4*)(lki + o * 32);
        #pragma unroll
        for (int ii = 0; ii < 8; ii++) {
            float4 kr = kr4[ii], ki = ki4[ii];   // same addr all lanes -> broadcast
            int i = ii * 4;
            tr0 += xr0[i+0]*kr.x - xi0[i+0]*ki.x;  ti0 += xr0[i+0]*ki.x + xi0[i+0]*kr.x;
            tr1 += xr1[i+0]*kr.x - xi1[i+0]*ki.x;  ti1 += xr1[i+0]*ki.x + xi1[i+0]*kr.x;
            tr0 += xr0[i+1]*kr.y - xi0[i+1]*ki.y;  ti0 += xr0[i+1]*ki.y + xi0[i+1]*kr.y;
            tr1 += xr1[i+1]*kr.y - xi1[i+1]*ki.y;  ti1 += xr1[i+1]*ki.y + xi1[i+1]*kr.y;
            tr0 += xr0[i+2]*kr.z - xi0[i+2]*ki.z;  ti0 += xr0[i+2]*ki.z + xi0[i+2]*kr.z;
            tr1 += xr1[i+2]*kr.z - xi1[i+2]*ki.z;  ti1 += xr1[i+2]*ki.z + xi1[i+2]*kr.z;
            tr0 += xr0[i+3]*kr.w - xi0[i+3]*ki.w;  ti0 += xr0[i+3]*ki.w + xi0[i+3]*kr.w;
            tr1 += xr1[i+3]*kr.w - xi1[i+3]*ki.w;  ti1 += xr1[i+3]*ki.w + xi1[i+3]*kr.w;
        }
        float cm0 = CmT[o * 8192 + rp0];
        float cm1 = CmT[o * 8192 + rp0 + 256];
        gr0 += cm0 * tr0; gi0 += cm0 * ti0;
        gr1 += cm1 * tr1; gi1 += cm1 * ti1;
    }
    gbuf[(x * 2) * 8192 + rp0]           = gr0;
    gbuf[(x * 2) * 8192 + rp0 + 256]     = gr1;
    gbuf[(x * 2 + 1) * 8192 + rp0]       = gi0;
    gbuf[(x * 2 + 1) * 8192 + rp0 + 256] = gi1;
}

// ---------------- irfft + D-skip + residual ----------------
__global__ __launch_bounds__(256) void k_inv(const float* __restrict__ gbuf,
                                             const float* __restrict__ ct,
                                             const float* __restrict__ st,
                                             const float* __restrict__ Dp,
                                             const float* __restrict__ xnT,
                                             float* __restrict__ encT,
                                             float* __restrict__ enc) {
    int d = blockIdx.x >> 5;
    int rp = (blockIdx.x & 31) * 256 + threadIdx.x;
    float acc = gbuf[rp];   // Re(g[0]); imag of DC dropped (C2R convention)
    for (int x = 1; x < 32; x++) {
        int k = (x * d) & 127;            // grid-uniform tables
        float c = ct[k], s = st[k];
        acc += 2.f * (gbuf[(x * 2) * 8192 + rp] * c - gbuf[(x * 2 + 1) * 8192 + rp] * s);
    }
    float ys = acc * (1.f / 128.f);
    float v = ys + Dp[d] * xnT[d * 8192 + rp] + encT[d * 8192 + rp];
    encT[d * 8192 + rp] = v;
    int bc = rp & 255, p = rp >> 8;
    enc[(bc * 32 + p) * 128 + d] = v;
}

// ---------------- head: ow transpose ----------------
__global__ void k_trans(const float* __restrict__ ow, float* __restrict__ owT) {
    int idx = blockIdx.x * 256 + threadIdx.x;  // < 786432
    int k = idx / 192, t = idx - k * 192;
    owT[idx] = ow[t * 4096 + k];               // owT[k][t]
}

// ---------------- head: K-split GEMM partials ----------------
// block = (bc-group of 16, k-chunk of 256); 192 threads (t on lanes)
__global__ __launch_bounds__(192) void k_head(const float* __restrict__ enc,
                                              const float* __restrict__ owT,
                                              float* __restrict__ pbuf) {
    int bcg = blockIdx.x >> 4;
    int kc  = blockIdx.x & 15;
    int t = threadIdx.x;
    int bc0 = bcg * 16, kk0 = kc * 256;
    __shared__ float el[256 * 20];             // [k_local][bc(16), pad to 20]
    for (int u = t; u < 4096; u += 192) {
        int b = u >> 8, kl = u & 255;
        el[kl * 20 + b] = enc[(bc0 + b) * 4096 + kk0 + kl];
    }
    __syncthreads();
    float acc[16];
    #pragma unroll
    for (int b = 0; b < 16; b++) acc[b] = 0.f;
    for (int kl = 0; kl < 256; kl++) {
        float w = owT[(kk0 + kl) * 192 + t];   // coalesced over lanes
        const float4* e4 = (const float4*)(el + kl * 20);  // broadcast reads
        #pragma unroll
        for (int q = 0; q < 4; q++) {
            float4 e = e4[q];
            acc[q * 4 + 0] += w * e.x;
            acc[q * 4 + 1] += w * e.y;
            acc[q * 4 + 2] += w * e.z;
            acc[q * 4 + 3] += w * e.w;
        }
    }
    #pragma unroll
    for (int b = 0; b < 16; b++)
        pbuf[(kc * 256 + bc0 + b) * 192 + t] = acc[b];
}

// ---------------- head: reduce partials + epilogue ----------------
__global__ void k_headred(const float* __restrict__ pbuf, const float* __restrict__ ob,
                          const float* __restrict__ stdev, const float* __restrict__ means,
                          float* __restrict__ out) {
    int idx = blockIdx.x * 256 + threadIdx.x;  // < 49152
    int bc = idx / 192, t = idx - bc * 192;
    float s = 0.f;
    #pragma unroll
    for (int kc = 0; kc < 16; kc++) s += pbuf[kc * 49152 + idx];
    int b = bc >> 5, c = bc & 31;
    out[(b * PREDq + t) * C0q + c] = (s + ob[t]) * stdev[bc] + means[bc];
}

extern "C" void kernel_launch(void* const* d_in, const int* in_sizes, int n_in,
                              void* d_out, int out_size, void* d_ws, size_t ws_size,
                              hipStream_t stream) {
    const float* x     = (const float*)d_in[0];
    const float* xproj = (const float*)d_in[4];
    const float* dtw   = (const float*)d_in[5];
    const float* dtb   = (const float*)d_in[6];
    const float* Alog  = (const float*)d_in[7];
    const float* Dp    = (const float*)d_in[8];
    const float* Kr    = (const float*)d_in[9];
    const float* Ki    = (const float*)d_in[10];
    const float* lng   = (const float*)d_in[11];
    const float* lnb   = (const float*)d_in[12];
    const float* ow    = (const float*)d_in[13];
    const float* ob    = (const float*)d_in[14];
    float* out = (float*)d_out;

    float* w = (float*)d_ws;
    float* means  = w; w += 256;
    float* stdev  = w; w += 256;
    float* tw     = w; w += 8192;
    float* ct     = w; w += 128;
    float* st     = w; w += 128;
    float* enc    = w; w += 1048576;   // [r][d]
    float* encT   = w; w += 1048576;   // [d][p][bc]
    float* xnT    = w; w += 1048576;   // [d][p][bc]
    float* deltaT = w; w += 1048576;   // [p][d][bc]
    float* BmT    = w; w += 262144;    // [p][s][bc]
    float* CmT    = w; w += 262144;    // [o][p][bc]
    float* gbuf   = w; w += 524288;    // [x*2+c][rp]
    float* xfb    = w; w += 16777216;  // [(x*2+c)*32+i][rp]
    float* hsT    = w; w += 33554432;  // [d][s][p][bc]
    // head scratch aliases xfb (dead after last k_mix)
    float* owT  = xfb;                 // 786432 floats
    float* pbuf = xfb + 786432;        // 786432 floats

    k_init<<<33, 256, 0, stream>>>(tw, ct, st);
    k_stats<<<256, 256, 0, stream>>>(x, means, stdev);
    k_embed<<<4096, 256, 0, stream>>>(x, means, stdev, enc, encT);
    for (int li = 0; li < ELq; li++) {
        k_lnproj<<<8192, 128, 0, stream>>>(enc, xproj + li * 9216, dtw + li * 1024,
                                           dtb + li * 128, lng + li * 128, lnb + li * 128,
                                           xnT, deltaT, BmT, CmT);
        k_scan<<<4096, 256, 0, stream>>>(deltaT, xnT, BmT, Alog + li * 4096, hsT);
        k_dft<<<1024, 256, 0, stream>>>(hsT, tw, xfb);
        k_mix<<<512, 256, 0, stream>>>(xfb, CmT, Kr + li * 32768, Ki + li * 32768, gbuf);
        k_inv<<<4096, 256, 0, stream>>>(gbuf, ct, st, Dp + li * 128, xnT, encT, enc);
    }
    k_trans<<<3072, 256, 0, stream>>>(ow, owT);
    k_head<<<256, 192, 0, stream>>>(enc, owT, pbuf);
    k_headred<<<192, 256, 0, stream>>>(pbuf, ob, stdev, means, out);
}

// Round 3
// 460.485 us; speedup vs baseline: 1.4231x; 1.2514x over previous
//
#include <hip/hip_runtime.h>

typedef __attribute__((ext_vector_type(8))) short s8;
typedef __attribute__((ext_vector_type(4))) float f4;

#define PREDq 192

__device__ inline short f2bf(float f) {
    union { float f; unsigned u; } v; v.f = f;
    unsigned r = (v.u + 0x7FFF + ((v.u >> 16) & 1)) >> 16;
    return (short)r;
}

// ---------------- init: twiddle tables ----------------
// twA: bf16 [ (x*2+c) ][ d ]  (A-operand for DFT MFMA): c==0 -> cos, c==1 -> -sin
__global__ void k_init(short* __restrict__ twA, float* __restrict__ ct, float* __restrict__ st) {
    int idx = blockIdx.x * 256 + threadIdx.x;
    if (idx < 8192) {
        int n = idx >> 7, d = idx & 127;
        int x = n >> 1, c = n & 1;
        float ang = (float)((x * d) & 127) * 0.04908738521234052f; // 2*pi/128
        twA[idx] = f2bf((c == 0) ? cosf(ang) : -sinf(ang));
    }
    if (idx < 128) {
        float ang = (float)idx * 0.04908738521234052f;
        ct[idx] = cosf(ang);
        st[idx] = sinf(ang);
    }
}

// ---------------- per-(b,c) mean/std over T ----------------
__global__ void k_stats(const float* __restrict__ x, float* __restrict__ means, float* __restrict__ stdev) {
    int bc = blockIdx.x;
    int b = bc >> 5, c = bc & 31;
    int t = threadIdx.x; // 256
    float s1 = 0.f, s2 = 0.f;
    for (int tt = t; tt < 512; tt += 256) {
        float v = x[(b * 512 + tt) * 32 + c];
        s1 += v; s2 += v * v;
    }
    #pragma unroll
    for (int off = 32; off > 0; off >>= 1) {
        s1 += __shfl_xor(s1, off);
        s2 += __shfl_xor(s2, off);
    }
    __shared__ float r1[4], r2[4];
    int wave = t >> 6, lane = t & 63;
    if (lane == 0) { r1[wave] = s1; r2[wave] = s2; }
    __syncthreads();
    if (t == 0) {
        float S1 = r1[0] + r1[1] + r1[2] + r1[3];
        float S2 = r2[0] + r2[1] + r2[2] + r2[3];
        float mu = S1 * (1.f / 512.f);
        float var = S2 * (1.f / 512.f) - mu * mu;
        means[bc] = mu;
        stdev[bc] = sqrtf(var + 1e-5f);
    }
}

// ---------------- PSR embedding ----------------
__global__ void k_embed(const float* __restrict__ x, const float* __restrict__ means,
                        const float* __restrict__ stdev, float* __restrict__ enc,
                        float* __restrict__ encT) {
    int idx = blockIdx.x * 256 + threadIdx.x; // < 1048576
    int bc = idx >> 12, rem = idx & 4095;
    int p = rem >> 7, dd = rem & 127;
    int m = dd >> 4, l = dd & 15;
    int b = bc >> 5, c = bc & 31;
    int t = p * 16 + l;
    float v = 0.f;
    if (t >= 7) v = (x[(b * 512 + (t - 7 + m)) * 32 + c] - means[bc]) / stdev[bc];
    enc[idx] = v;                               // [r=(bc*32+p)][d]
    encT[(dd * 32 + p) * 256 + bc] = v;         // [d][rp]
}

// ---------------- LayerNorm + projections ----------------
__global__ void k_lnproj(const float* __restrict__ enc,
                         const float* __restrict__ xw,   // (72,128)
                         const float* __restrict__ dw,   // (128,8)
                         const float* __restrict__ db,   // (128)
                         const float* __restrict__ g, const float* __restrict__ bb,
                         float* __restrict__ xnT,        // [d][rp]
                         float* __restrict__ xnR,        // [rp][d]
                         float* __restrict__ deltaT,     // [rp][d]
                         float* __restrict__ BmT,        // [p][s][bc]
                         float* __restrict__ CmT) {      // [o][rp]
    int r = blockIdx.x;          // bc*32+p
    int bc = r >> 5, p = r & 31;
    int rp = p * 256 + bc;
    int t = threadIdx.x;         // 128
    __shared__ float xs[128];
    __shared__ float red[4];
    __shared__ float dr[8];
    float e = enc[r * 128 + t];
    float s1 = e, s2 = e * e;
    #pragma unroll
    for (int off = 32; off > 0; off >>= 1) {
        s1 += __shfl_xor(s1, off);
        s2 += __shfl_xor(s2, off);
    }
    if ((t & 63) == 0) { red[(t >> 6) * 2] = s1; red[(t >> 6) * 2 + 1] = s2; }
    __syncthreads();
    float mu = (red[0] + red[2]) * (1.f / 128.f);
    float var = (red[1] + red[3]) * (1.f / 128.f) - mu * mu;
    float inv = rsqrtf(var + 1e-5f);
    float v = (e - mu) * inv * g[t] + bb[t];
    xs[t] = v;
    xnT[(t * 32 + p) * 256 + bc] = v;
    xnR[rp * 128 + t] = v;
    __syncthreads();
    if (t < 72) {
        float acc = 0.f;
        const float* w = xw + t * 128;
        #pragma unroll 8
        for (int d = 0; d < 128; d++) acc += xs[d] * w[d];
        if (t < 8) dr[t] = acc;
        else if (t < 40) BmT[(p * 32 + (t - 8)) * 256 + bc] = acc;
        else CmT[(t - 40) * 8192 + rp] = acc;
    }
    __syncthreads();
    float a = db[t];
    const float* wd = dw + t * 8;
    #pragma unroll
    for (int rr = 0; rr < 8; rr++) a += dr[rr] * wd[rr];
    float sp = fmaxf(a, 0.f) + log1pf(expf(-fabsf(a)));  // stable softplus
    deltaT[rp * 128 + t] = sp;
}

// ---------------- selective scan; emits bf16 hs in [rowA=(s,p,bc)][d] ----------------
__global__ __launch_bounds__(256) void k_scan(const float* __restrict__ deltaT,  // [rp][d]
                                              const float* __restrict__ xnR,     // [rp][d]
                                              const float* __restrict__ BmT,     // [p][s][bc]
                                              const float* __restrict__ Alog,
                                              short* __restrict__ hsA) {         // bf16 [rowA][d]
    int s = blockIdx.x >> 7;
    int bc0 = (blockIdx.x & 127) * 2;
    int t = threadIdx.x;
    int d = t & 127, bcl = t >> 7, bc = bc0 + bcl;
    float A = -expf(Alog[d * 32 + s]);
    float h = 0.f;
    for (int p = 0; p < 32; p++) {
        int rp = p * 256 + bc;
        float dl = deltaT[rp * 128 + d];
        float xv = xnR[rp * 128 + d];
        float bv = BmT[(p * 32 + s) * 256 + bc];
        h = expf(dl * A) * h + dl * xv * bv;
        hsA[((s * 32 + p) * 256 + bc) * 128 + d] = f2bf(h);
    }
}

// ---------------- DFT via MFMA: xf[m=(x,c)][rowA] = tw[m][d] * hs[d][rowA] ----------------
__global__ __launch_bounds__(256) void k_dft(const short* __restrict__ hsA,
                                             const short* __restrict__ twA,
                                             float* __restrict__ xf) {
    int wave = threadIdx.x >> 6, lane = threadIdx.x & 63;
    int l15 = lane & 15, q = lane >> 4;
    // A fragments (constant twiddles): A[m=l15][k=q*8+j]
    s8 afr[4][4];
    #pragma unroll
    for (int mt = 0; mt < 4; mt++)
        #pragma unroll
        for (int kt = 0; kt < 4; kt++)
            afr[mt][kt] = *(const s8*)(twA + (mt * 16 + l15) * 128 + kt * 32 + q * 8);
    int tile0 = (blockIdx.x * 4 + wave) * 4;   // 4 tiles of 16 rows per wave
    for (int j = 0; j < 4; j++) {
        int n0 = (tile0 + j) * 16;
        f4 acc0 = {0.f, 0.f, 0.f, 0.f}, acc1 = acc0, acc2 = acc0, acc3 = acc0;
        #pragma unroll
        for (int kt = 0; kt < 4; kt++) {
            // B[k=q*8+j][n=l15] from hsA[row][d]
            s8 b = *(const s8*)(hsA + (n0 + l15) * 128 + kt * 32 + q * 8);
            acc0 = __builtin_amdgcn_mfma_f32_16x16x32_bf16(afr[0][kt], b, acc0, 0, 0, 0);
            acc1 = __builtin_amdgcn_mfma_f32_16x16x32_bf16(afr[1][kt], b, acc1, 0, 0, 0);
            acc2 = __builtin_amdgcn_mfma_f32_16x16x32_bf16(afr[2][kt], b, acc2, 0, 0, 0);
            acc3 = __builtin_amdgcn_mfma_f32_16x16x32_bf16(afr[3][kt], b, acc3, 0, 0, 0);
        }
        // D[row=q*4+r][col=l15]; store to xf[(m)*262144 + rowA]
        #pragma unroll
        for (int r = 0; r < 4; r++) {
            xf[(q * 4 + r) * 262144 + n0 + l15]        = acc0[r];
            xf[(16 + q * 4 + r) * 262144 + n0 + l15]   = acc1[r];
            xf[(32 + q * 4 + r) * 262144 + n0 + l15]   = acc2[r];
            xf[(48 + q * 4 + r) * 262144 + n0 + l15]   = acc3[r];
        }
    }
}

// ---------------- mode mixing: u = K·Cm (real·real), then g = <xf, u> ----------------
__global__ __launch_bounds__(256) void k_mix(const float* __restrict__ xf,   // [(x2c)*32+i][rp]
                                             const float* __restrict__ CmT,  // [o][rp]
                                             const float* __restrict__ Kr,
                                             const float* __restrict__ Ki,
                                             float* __restrict__ gbuf) {     // [x2c][rp]
    int x = blockIdx.x >> 5;
    int rp = (blockIdx.x & 31) * 256 + threadIdx.x;
    __shared__ float lkr[1024], lki[1024];             // [o][i]
    for (int u = threadIdx.x; u < 1024; u += 256) {
        int o = u >> 5, i = u & 31;
        lkr[u] = Kr[(i * 32 + o) * 32 + x];
        lki[u] = Ki[(i * 32 + o) * 32 + x];
    }
    __syncthreads();
    float ur[32], ui[32];
    #pragma unroll
    for (int i = 0; i < 32; i++) { ur[i] = 0.f; ui[i] = 0.f; }
    for (int o = 0; o < 32; o++) {
        float co = CmT[o * 8192 + rp];
        const f4* kr4 = (const f4*)(lkr + o * 32);
        const f4* ki4 = (const f4*)(lki + o * 32);
        #pragma unroll
        for (int ii = 0; ii < 8; ii++) {
            f4 kr = kr4[ii], ki = ki4[ii];   // broadcast LDS reads
            ur[ii * 4 + 0] += co * kr[0];  ui[ii * 4 + 0] += co * ki[0];
            ur[ii * 4 + 1] += co * kr[1];  ui[ii * 4 + 1] += co * ki[1];
            ur[ii * 4 + 2] += co * kr[2];  ui[ii * 4 + 2] += co * ki[2];
            ur[ii * 4 + 3] += co * kr[3];  ui[ii * 4 + 3] += co * ki[3];
        }
    }
    float gr = 0.f, gi = 0.f;
    const float* pr = xf + (x * 64) * 262144 / 32 * 32 + (x * 2 + 0) * 0;  // (kept simple below)
    #pragma unroll
    for (int i = 0; i < 32; i++) {
        float xr = xf[((x * 2 + 0) * 32 + i) * 8192 + rp];
        float xi = xf[((x * 2 + 1) * 32 + i) * 8192 + rp];
        gr += xr * ur[i] - xi * ui[i];
        gi += xr * ui[i] + xi * ur[i];
    }
    (void)pr;
    gbuf[(x * 2 + 0) * 8192 + rp] = gr;
    gbuf[(x * 2 + 1) * 8192 + rp] = gi;
}

// ---------------- irfft + D-skip + residual ----------------
__global__ __launch_bounds__(256) void k_inv(const float* __restrict__ gbuf,
                                             const float* __restrict__ ct,
                                             const float* __restrict__ st,
                                             const float* __restrict__ Dp,
                                             const float* __restrict__ xnT,
                                             float* __restrict__ encT,
                                             float* __restrict__ enc) {
    int d = blockIdx.x >> 5;
    int rp = (blockIdx.x & 31) * 256 + threadIdx.x;
    float acc = gbuf[rp];   // Re(g[0]); imag of DC dropped (C2R convention)
    for (int x = 1; x < 32; x++) {
        int k = (x * d) & 127;
        float c = ct[k], s = st[k];
        acc += 2.f * (gbuf[(x * 2) * 8192 + rp] * c - gbuf[(x * 2 + 1) * 8192 + rp] * s);
    }
    float ys = acc * (1.f / 128.f);
    float v = ys + Dp[d] * xnT[d * 8192 + rp] + encT[d * 8192 + rp];
    encT[d * 8192 + rp] = v;
    int bc = rp & 255, p = rp >> 8;
    enc[(bc * 32 + p) * 128 + d] = v;
}

// ---------------- head: ow transpose ----------------
__global__ void k_trans(const float* __restrict__ ow, float* __restrict__ owT) {
    int idx = blockIdx.x * 256 + threadIdx.x;  // < 786432
    int k = idx / 192, t = idx - k * 192;
    owT[idx] = ow[t * 4096 + k];               // owT[k][t]
}

// ---------------- head: K-split GEMM partials ----------------
__global__ __launch_bounds__(192) void k_head(const float* __restrict__ enc,
                                              const float* __restrict__ owT,
                                              float* __restrict__ pbuf) {
    int bcg = blockIdx.x >> 4;
    int kc  = blockIdx.x & 15;
    int t = threadIdx.x;
    int bc0 = bcg * 16, kk0 = kc * 256;
    __shared__ float el[256 * 20];
    for (int u = t; u < 4096; u += 192) {
        int b = u >> 8, kl = u & 255;
        el[kl * 20 + b] = enc[(bc0 + b) * 4096 + kk0 + kl];
    }
    __syncthreads();
    float acc[16];
    #pragma unroll
    for (int b = 0; b < 16; b++) acc[b] = 0.f;
    for (int kl = 0; kl < 256; kl++) {
        float w = owT[(kk0 + kl) * 192 + t];
        const f4* e4 = (const f4*)(el + kl * 20);
        #pragma unroll
        for (int q = 0; q < 4; q++) {
            f4 e = e4[q];
            acc[q * 4 + 0] += w * e[0];
            acc[q * 4 + 1] += w * e[1];
            acc[q * 4 + 2] += w * e[2];
            acc[q * 4 + 3] += w * e[3];
        }
    }
    #pragma unroll
    for (int b = 0; b < 16; b++)
        pbuf[(kc * 256 + bc0 + b) * 192 + t] = acc[b];
}

// ---------------- head: reduce partials + epilogue ----------------
__global__ void k_headred(const float* __restrict__ pbuf, const float* __restrict__ ob,
                          const float* __restrict__ stdev, const float* __restrict__ means,
                          float* __restrict__ out) {
    int idx = blockIdx.x * 256 + threadIdx.x;  // < 49152
    int bc = idx / 192, t = idx - bc * 192;
    float s = 0.f;
    #pragma unroll
    for (int kc = 0; kc < 16; kc++) s += pbuf[kc * 49152 + idx];
    int b = bc >> 5, c = bc & 31;
    out[(b * PREDq + t) * 32 + c] = (s + ob[t]) * stdev[bc] + means[bc];
}

extern "C" void kernel_launch(void* const* d_in, const int* in_sizes, int n_in,
                              void* d_out, int out_size, void* d_ws, size_t ws_size,
                              hipStream_t stream) {
    const float* x     = (const float*)d_in[0];
    const float* xproj = (const float*)d_in[4];
    const float* dtw   = (const float*)d_in[5];
    const float* dtb   = (const float*)d_in[6];
    const float* Alog  = (const float*)d_in[7];
    const float* Dp    = (const float*)d_in[8];
    const float* Kr    = (const float*)d_in[9];
    const float* Ki    = (const float*)d_in[10];
    const float* lng   = (const float*)d_in[11];
    const float* lnb   = (const float*)d_in[12];
    const float* ow    = (const float*)d_in[13];
    const float* ob    = (const float*)d_in[14];
    float* out = (float*)d_out;

    float* w = (float*)d_ws;
    float* means  = w; w += 256;
    float* stdev  = w; w += 256;
    short* twA    = (short*)w; w += 4096;   // 8192 bf16
    float* ct     = w; w += 128;
    float* st     = w; w += 128;
    float* enc    = w; w += 1048576;   // [r][d]
    float* encT   = w; w += 1048576;   // [d][rp]
    float* xnT    = w; w += 1048576;   // [d][rp]
    float* xnR    = w; w += 1048576;   // [rp][d]
    float* deltaT = w; w += 1048576;   // [rp][d]
    float* BmT    = w; w += 262144;    // [p][s][bc]
    float* CmT    = w; w += 262144;    // [o][rp]
    float* gbuf   = w; w += 524288;    // [x2c][rp]
    float* xfb    = w; w += 16777216;  // [(x2c)*32+i][rp]
    short* hsA    = (short*)w; w += 8388608;  // bf16 [rowA=(s,p,bc)][d]
    float* owT  = xfb;                 // head scratch aliases xfb
    float* pbuf = xfb + 786432;

    k_init<<<33, 256, 0, stream>>>(twA, ct, st);
    k_stats<<<256, 256, 0, stream>>>(x, means, stdev);
    k_embed<<<4096, 256, 0, stream>>>(x, means, stdev, enc, encT);
    for (int li = 0; li < 2; li++) {
        k_lnproj<<<8192, 128, 0, stream>>>(enc, xproj + li * 9216, dtw + li * 1024,
                                           dtb + li * 128, lng + li * 128, lnb + li * 128,
                                           xnT, xnR, deltaT, BmT, CmT);
        k_scan<<<4096, 256, 0, stream>>>(deltaT, xnR, BmT, Alog + li * 4096, hsA);
        k_dft<<<1024, 256, 0, stream>>>(hsA, twA, xfb);
        k_mix<<<1024, 256, 0, stream>>>(xfb, CmT, Kr + li * 32768, Ki + li * 32768, gbuf);
        k_inv<<<4096, 256, 0, stream>>>(gbuf, ct, st, Dp + li * 128, xnT, encT, enc);
    }
    k_trans<<<3072, 256, 0, stream>>>(ow, owT);
    k_head<<<256, 192, 0, stream>>>(enc, owT, pbuf);
    k_headred<<<192, 256, 0, stream>>>(pbuf, ob, stdev, means, out);
}

// Round 4
// 431.606 us; speedup vs baseline: 1.5183x; 1.0669x over previous
//
#include <hip/hip_runtime.h>

typedef __attribute__((ext_vector_type(8))) short s8;
typedef __attribute__((ext_vector_type(4))) float f4;

#define PREDq 192

__device__ inline short f2bf(float f) {
    union { float f; unsigned u; } v; v.f = f;
    unsigned r = (v.u + 0x7FFF + ((v.u >> 16) & 1)) >> 16;
    return (short)r;
}
__device__ inline float bf2f(short h) {
    union { unsigned u; float f; } v;
    v.u = ((unsigned)(unsigned short)h) << 16;
    return v.f;
}

// ---------------- init: twiddle tables ----------------
// twA: bf16 [ (x*2+c) ][ d ]  (A-operand for DFT MFMA): c==0 -> cos, c==1 -> -sin
__global__ void k_init(short* __restrict__ twA, float* __restrict__ ct, float* __restrict__ st) {
    int idx = blockIdx.x * 256 + threadIdx.x;
    if (idx < 8192) {
        int n = idx >> 7, d = idx & 127;
        int x = n >> 1, c = n & 1;
        float ang = (float)((x * d) & 127) * 0.04908738521234052f; // 2*pi/128
        twA[idx] = f2bf((c == 0) ? cosf(ang) : -sinf(ang));
    }
    if (idx < 128) {
        float ang = (float)idx * 0.04908738521234052f;
        ct[idx] = cosf(ang);
        st[idx] = sinf(ang);
    }
}

// ---------------- weight transposes (both layers) ----------------
__global__ void k_wt(const float* __restrict__ xw, const float* __restrict__ dw,
                     float* __restrict__ xwT, float* __restrict__ dwT) {
    int idx = blockIdx.x * 256 + threadIdx.x;
    if (idx < 2 * 128 * 80) {           // xwT[li][d][80]
        int li = idx / 10240, rem = idx % 10240, d = rem / 80, t = rem % 80;
        xwT[idx] = (t < 72) ? xw[li * 9216 + t * 128 + d] : 0.f;
    }
    if (idx < 2 * 8 * 128) {            // dwT[li][r][128]
        int li = idx / 1024, rem = idx % 1024, r = rem / 128, d = rem % 128;
        dwT[idx] = dw[li * 1024 + d * 8 + r];
    }
}

// ---------------- per-(b,c) mean/std over T ----------------
__global__ void k_stats(const float* __restrict__ x, float* __restrict__ means, float* __restrict__ stdev) {
    int bc = blockIdx.x;
    int b = bc >> 5, c = bc & 31;
    int t = threadIdx.x; // 256
    float s1 = 0.f, s2 = 0.f;
    for (int tt = t; tt < 512; tt += 256) {
        float v = x[(b * 512 + tt) * 32 + c];
        s1 += v; s2 += v * v;
    }
    #pragma unroll
    for (int off = 32; off > 0; off >>= 1) {
        s1 += __shfl_xor(s1, off);
        s2 += __shfl_xor(s2, off);
    }
    __shared__ float r1[4], r2[4];
    int wave = t >> 6, lane = t & 63;
    if (lane == 0) { r1[wave] = s1; r2[wave] = s2; }
    __syncthreads();
    if (t == 0) {
        float S1 = r1[0] + r1[1] + r1[2] + r1[3];
        float S2 = r2[0] + r2[1] + r2[2] + r2[3];
        float mu = S1 * (1.f / 512.f);
        float var = S2 * (1.f / 512.f) - mu * mu;
        means[bc] = mu;
        stdev[bc] = sqrtf(var + 1e-5f);
    }
}

// ---------------- PSR embedding ----------------
__global__ void k_embed(const float* __restrict__ x, const float* __restrict__ means,
                        const float* __restrict__ stdev, float* __restrict__ enc,
                        float* __restrict__ encT) {
    int idx = blockIdx.x * 256 + threadIdx.x; // < 1048576
    int bc = idx >> 12, rem = idx & 4095;
    int p = rem >> 7, dd = rem & 127;
    int m = dd >> 4, l = dd & 15;
    int b = bc >> 5, c = bc & 31;
    int t = p * 16 + l;
    float v = 0.f;
    if (t >= 7) v = (x[(b * 512 + (t - 7 + m)) * 32 + c] - means[bc]) / stdev[bc];
    enc[idx] = v;                               // [r=(bc*32+p)][d]
    encT[(dd * 32 + p) * 256 + bc] = v;         // [d][rp]
}

// ---------------- LayerNorm + projections (coalesced weights) ----------------
__global__ __launch_bounds__(128) void k_lnproj(const float* __restrict__ enc,
                         const float* __restrict__ xwT,  // [d][80]
                         const float* __restrict__ dwT,  // [r][128]
                         const float* __restrict__ db,   // (128)
                         const float* __restrict__ g, const float* __restrict__ bb,
                         float* __restrict__ xnT,        // [d][rp]
                         float* __restrict__ xnR,        // [rp][d]
                         float* __restrict__ deltaT,     // [rp][d]
                         float* __restrict__ BmT,        // [p][s][bc]
                         float* __restrict__ CmT) {      // [o][rp]
    int r = blockIdx.x;          // bc*32+p
    int bc = r >> 5, p = r & 31;
    int rp = p * 256 + bc;
    int t = threadIdx.x;         // 128
    __shared__ float xs[128];
    __shared__ float red[4];
    __shared__ float dr[8];
    float e = enc[r * 128 + t];
    float s1 = e, s2 = e * e;
    #pragma unroll
    for (int off = 32; off > 0; off >>= 1) {
        s1 += __shfl_xor(s1, off);
        s2 += __shfl_xor(s2, off);
    }
    if ((t & 63) == 0) { red[(t >> 6) * 2] = s1; red[(t >> 6) * 2 + 1] = s2; }
    __syncthreads();
    float mu = (red[0] + red[2]) * (1.f / 128.f);
    float var = (red[1] + red[3]) * (1.f / 128.f) - mu * mu;
    float inv = rsqrtf(var + 1e-5f);
    float v = (e - mu) * inv * g[t] + bb[t];
    xs[t] = v;
    xnT[(t * 32 + p) * 256 + bc] = v;
    xnR[rp * 128 + t] = v;
    __syncthreads();
    if (t < 80) {
        float acc = 0.f;
        const f4* xs4 = (const f4*)xs;
        #pragma unroll 8
        for (int dq = 0; dq < 32; dq++) {
            f4 xv = xs4[dq];                     // LDS broadcast (b128)
            const float* wp = xwT + dq * 320 + t;  // coalesced over lanes
            acc += xv[0] * wp[0] + xv[1] * wp[80] + xv[2] * wp[160] + xv[3] * wp[240];
        }
        if (t < 8) dr[t] = acc;
        else if (t < 40) BmT[(p * 32 + (t - 8)) * 256 + bc] = acc;
        else if (t < 72) CmT[(t - 40) * 8192 + rp] = acc;
    }
    __syncthreads();
    float a = db[t];
    #pragma unroll
    for (int rr = 0; rr < 8; rr++) a += dr[rr] * dwT[rr * 128 + t];  // coalesced
    float sp = fmaxf(a, 0.f) + log1pf(expf(-fabsf(a)));  // stable softplus
    deltaT[rp * 128 + t] = sp;
}

// ---------------- selective scan; 8 s-states per thread ----------------
__global__ __launch_bounds__(256) void k_scan(const float* __restrict__ deltaT,  // [rp][d]
                                              const float* __restrict__ xnR,     // [rp][d]
                                              const float* __restrict__ BmT,     // [p][s][bc]
                                              const float* __restrict__ Alog,
                                              short* __restrict__ hsA) {         // bf16 [rowA=(s,p,bc)][d]
    int sg = blockIdx.x >> 7;               // 4 groups of 8 s
    int bc0 = (blockIdx.x & 127) * 2;
    int t = threadIdx.x;
    int d = t & 127, bcl = t >> 7, bc = bc0 + bcl;
    int s0 = sg * 8;
    float A[8], h[8];
    #pragma unroll
    for (int j = 0; j < 8; j++) {
        A[j] = -__expf(Alog[d * 32 + s0 + j]);
        h[j] = 0.f;
    }
    for (int p = 0; p < 32; p++) {
        int rp = p * 256 + bc;
        float dl = deltaT[rp * 128 + d];
        float xv = xnR[rp * 128 + d];
        float dx = dl * xv;
        #pragma unroll
        for (int j = 0; j < 8; j++) {
            float bv = BmT[(p * 32 + s0 + j) * 256 + bc];   // 2 addrs/wave -> 1 txn
            h[j] = __expf(dl * A[j]) * h[j] + dx * bv;
            hsA[(((s0 + j) * 32 + p) * 256 + bc) * 128 + d] = f2bf(h[j]);
        }
    }
}

// ---------------- DFT via MFMA: xf[m=(x,c)][rowA] = tw[m][d] * hs[d][rowA] ----------------
__global__ __launch_bounds__(256) void k_dft(const short* __restrict__ hsA,
                                             const short* __restrict__ twA,
                                             short* __restrict__ xfh) {
    int wave = threadIdx.x >> 6, lane = threadIdx.x & 63;
    int l15 = lane & 15, q = lane >> 4;
    // A fragments (constant twiddles): A[m=l15][k=q*8+j]
    s8 afr[4][4];
    #pragma unroll
    for (int mt = 0; mt < 4; mt++)
        #pragma unroll
        for (int kt = 0; kt < 4; kt++)
            afr[mt][kt] = *(const s8*)(twA + (mt * 16 + l15) * 128 + kt * 32 + q * 8);
    int tile0 = (blockIdx.x * 4 + wave) * 4;   // 4 tiles of 16 rows per wave
    for (int j = 0; j < 4; j++) {
        int n0 = (tile0 + j) * 16;
        f4 acc0 = {0.f, 0.f, 0.f, 0.f}, acc1 = acc0, acc2 = acc0, acc3 = acc0;
        #pragma unroll
        for (int kt = 0; kt < 4; kt++) {
            // B[k=q*8+j][n=l15] from hsA[row][d]
            s8 b = *(const s8*)(hsA + (n0 + l15) * 128 + kt * 32 + q * 8);
            acc0 = __builtin_amdgcn_mfma_f32_16x16x32_bf16(afr[0][kt], b, acc0, 0, 0, 0);
            acc1 = __builtin_amdgcn_mfma_f32_16x16x32_bf16(afr[1][kt], b, acc1, 0, 0, 0);
            acc2 = __builtin_amdgcn_mfma_f32_16x16x32_bf16(afr[2][kt], b, acc2, 0, 0, 0);
            acc3 = __builtin_amdgcn_mfma_f32_16x16x32_bf16(afr[3][kt], b, acc3, 0, 0, 0);
        }
        // D[row=q*4+r][col=l15]
        #pragma unroll
        for (int r = 0; r < 4; r++) {
            xfh[(q * 4 + r) * 262144 + n0 + l15]      = f2bf(acc0[r]);
            xfh[(16 + q * 4 + r) * 262144 + n0 + l15] = f2bf(acc1[r]);
            xfh[(32 + q * 4 + r) * 262144 + n0 + l15] = f2bf(acc2[r]);
            xfh[(48 + q * 4 + r) * 262144 + n0 + l15] = f2bf(acc3[r]);
        }
    }
}

// ---------------- mode mixing: u = K·Cm (real·real), then g = <xf, u> ----------------
__global__ __launch_bounds__(256) void k_mix(const short* __restrict__ xfh,  // bf16 [(x2c)*32+i][rp]
                                             const float* __restrict__ CmT,  // [o][rp]
                                             const float* __restrict__ Kr,
                                             const float* __restrict__ Ki,
                                             float* __restrict__ gbuf) {     // [x2c][rp]
    int x = blockIdx.x >> 5;
    int rp = (blockIdx.x & 31) * 256 + threadIdx.x;
    __shared__ float lkr[1024], lki[1024];             // [o][i]
    for (int u = threadIdx.x; u < 1024; u += 256) {
        int o = u >> 5, i = u & 31;
        lkr[u] = Kr[(i * 32 + o) * 32 + x];
        lki[u] = Ki[(i * 32 + o) * 32 + x];
    }
    __syncthreads();
    float ur[32], ui[32];
    #pragma unroll
    for (int i = 0; i < 32; i++) { ur[i] = 0.f; ui[i] = 0.f; }
    for (int o = 0; o < 32; o++) {
        float co = CmT[o * 8192 + rp];
        const f4* kr4 = (const f4*)(lkr + o * 32);
        const f4* ki4 = (const f4*)(lki + o * 32);
        #pragma unroll
        for (int ii = 0; ii < 8; ii++) {
            f4 kr = kr4[ii], ki = ki4[ii];   // broadcast LDS reads
            ur[ii * 4 + 0] += co * kr[0];  ui[ii * 4 + 0] += co * ki[0];
            ur[ii * 4 + 1] += co * kr[1];  ui[ii * 4 + 1] += co * ki[1];
            ur[ii * 4 + 2] += co * kr[2];  ui[ii * 4 + 2] += co * ki[2];
            ur[ii * 4 + 3] += co * kr[3];  ui[ii * 4 + 3] += co * ki[3];
        }
    }
    float gr = 0.f, gi = 0.f;
    #pragma unroll
    for (int i = 0; i < 32; i++) {
        float xr = bf2f(xfh[((x * 2 + 0) * 32 + i) * 8192 + rp]);
        float xi = bf2f(xfh[((x * 2 + 1) * 32 + i) * 8192 + rp]);
        gr += xr * ur[i] - xi * ui[i];
        gi += xr * ui[i] + xi * ur[i];
    }
    gbuf[(x * 2 + 0) * 8192 + rp] = gr;
    gbuf[(x * 2 + 1) * 8192 + rp] = gi;
}

// ---------------- irfft + D-skip + residual ----------------
__global__ __launch_bounds__(256) void k_inv(const float* __restrict__ gbuf,
                                             const float* __restrict__ ct,
                                             const float* __restrict__ st,
                                             const float* __restrict__ Dp,
                                             const float* __restrict__ xnT,
                                             float* __restrict__ encT,
                                             float* __restrict__ enc) {
    int d = blockIdx.x >> 5;
    int rp = (blockIdx.x & 31) * 256 + threadIdx.x;
    float acc = gbuf[rp];   // Re(g[0]); imag of DC dropped (C2R convention)
    for (int x = 1; x < 32; x++) {
        int k = (x * d) & 127;
        float c = ct[k], s = st[k];
        acc += 2.f * (gbuf[(x * 2) * 8192 + rp] * c - gbuf[(x * 2 + 1) * 8192 + rp] * s);
    }
    float ys = acc * (1.f / 128.f);
    float v = ys + Dp[d] * xnT[d * 8192 + rp] + encT[d * 8192 + rp];
    encT[d * 8192 + rp] = v;
    int bc = rp & 255, p = rp >> 8;
    enc[(bc * 32 + p) * 128 + d] = v;
}

// ---------------- head: ow transpose ----------------
__global__ void k_trans(const float* __restrict__ ow, float* __restrict__ owT) {
    int idx = blockIdx.x * 256 + threadIdx.x;  // < 786432
    int k = idx / 192, t = idx - k * 192;
    owT[idx] = ow[t * 4096 + k];               // owT[k][t]
}

// ---------------- head: K-split GEMM partials ----------------
__global__ __launch_bounds__(192) void k_head(const float* __restrict__ enc,
                                              const float* __restrict__ owT,
                                              float* __restrict__ pbuf) {
    int bcg = blockIdx.x >> 4;
    int kc  = blockIdx.x & 15;
    int t = threadIdx.x;
    int bc0 = bcg * 16, kk0 = kc * 256;
    __shared__ float el[256 * 20];
    for (int u = t; u < 4096; u += 192) {
        int b = u >> 8, kl = u & 255;
        el[kl * 20 + b] = enc[(bc0 + b) * 4096 + kk0 + kl];
    }
    __syncthreads();
    float acc[16];
    #pragma unroll
    for (int b = 0; b < 16; b++) acc[b] = 0.f;
    for (int kl = 0; kl < 256; kl++) {
        float w = owT[(kk0 + kl) * 192 + t];
        const f4* e4 = (const f4*)(el + kl * 20);
        #pragma unroll
        for (int q = 0; q < 4; q++) {
            f4 e = e4[q];
            acc[q * 4 + 0] += w * e[0];
            acc[q * 4 + 1] += w * e[1];
            acc[q * 4 + 2] += w * e[2];
            acc[q * 4 + 3] += w * e[3];
        }
    }
    #pragma unroll
    for (int b = 0; b < 16; b++)
        pbuf[(kc * 256 + bc0 + b) * 192 + t] = acc[b];
}

// ---------------- head: reduce partials + epilogue ----------------
__global__ void k_headred(const float* __restrict__ pbuf, const float* __restrict__ ob,
                          const float* __restrict__ stdev, const float* __restrict__ means,
                          float* __restrict__ out) {
    int idx = blockIdx.x * 256 + threadIdx.x;  // < 49152
    int bc = idx / 192, t = idx - bc * 192;
    float s = 0.f;
    #pragma unroll
    for (int kc = 0; kc < 16; kc++) s += pbuf[kc * 49152 + idx];
    int b = bc >> 5, c = bc & 31;
    out[(b * PREDq + t) * 32 + c] = (s + ob[t]) * stdev[bc] + means[bc];
}

extern "C" void kernel_launch(void* const* d_in, const int* in_sizes, int n_in,
                              void* d_out, int out_size, void* d_ws, size_t ws_size,
                              hipStream_t stream) {
    const float* x     = (const float*)d_in[0];
    const float* xproj = (const float*)d_in[4];
    const float* dtw   = (const float*)d_in[5];
    const float* dtb   = (const float*)d_in[6];
    const float* Alog  = (const float*)d_in[7];
    const float* Dp    = (const float*)d_in[8];
    const float* Kr    = (const float*)d_in[9];
    const float* Ki    = (const float*)d_in[10];
    const float* lng   = (const float*)d_in[11];
    const float* lnb   = (const float*)d_in[12];
    const float* ow    = (const float*)d_in[13];
    const float* ob    = (const float*)d_in[14];
    float* out = (float*)d_out;

    float* w = (float*)d_ws;
    float* means  = w; w += 256;
    float* stdev  = w; w += 256;
    short* twA    = (short*)w; w += 4096;   // 8192 bf16
    float* ct     = w; w += 128;
    float* st     = w; w += 128;
    float* xwT    = w; w += 20480;     // [li][d][80]
    float* dwT    = w; w += 2048;      // [li][r][128]
    float* enc    = w; w += 1048576;   // [r][d]
    float* encT   = w; w += 1048576;   // [d][rp]
    float* xnT    = w; w += 1048576;   // [d][rp]
    float* xnR    = w; w += 1048576;   // [rp][d]
    float* deltaT = w; w += 1048576;   // [rp][d]
    float* BmT    = w; w += 262144;    // [p][s][bc]
    float* CmT    = w; w += 262144;    // [o][rp]
    float* gbuf   = w; w += 524288;    // [x2c][rp]
    short* xfh    = (short*)w; w += 8388608;   // bf16 [(x2c)*32+i][rp]
    short* hsA    = (short*)w; w += 8388608;   // bf16 [rowA=(s,p,bc)][d]
    // head scratch aliases xfh region (dead after last k_mix)
    float* owT  = (float*)xfh;         // 786432 floats
    float* pbuf = ((float*)xfh) + 786432;

    k_init<<<33, 256, 0, stream>>>(twA, ct, st);
    k_wt<<<80, 256, 0, stream>>>(xproj, dtw, xwT, dwT);
    k_stats<<<256, 256, 0, stream>>>(x, means, stdev);
    k_embed<<<4096, 256, 0, stream>>>(x, means, stdev, enc, encT);
    for (int li = 0; li < 2; li++) {
        k_lnproj<<<8192, 128, 0, stream>>>(enc, xwT + li * 10240, dwT + li * 1024,
                                           dtb + li * 128, lng + li * 128, lnb + li * 128,
                                           xnT, xnR, deltaT, BmT, CmT);
        k_scan<<<512, 256, 0, stream>>>(deltaT, xnR, BmT, Alog + li * 4096, hsA);
        k_dft<<<1024, 256, 0, stream>>>(hsA, twA, xfh);
        k_mix<<<1024, 256, 0, stream>>>(xfh, CmT, Kr + li * 32768, Ki + li * 32768, gbuf);
        k_inv<<<4096, 256, 0, stream>>>(gbuf, ct, st, Dp + li * 128, xnT, encT, enc);
    }
    k_trans<<<3072, 256, 0, stream>>>(ow, owT);
    k_head<<<256, 192, 0, stream>>>(enc, owT, pbuf);
    k_headred<<<192, 256, 0, stream>>>(pbuf, ob, stdev, means, out);
}

// Round 5
// 396.415 us; speedup vs baseline: 1.6531x; 1.0888x over previous
//
#include <hip/hip_runtime.h>

typedef __attribute__((ext_vector_type(8))) short s8;
typedef __attribute__((ext_vector_type(4))) float f4;

#define PREDq 192

__device__ inline short f2bf(float f) {
    union { float f; unsigned u; } v; v.f = f;
    unsigned r = (v.u + 0x7FFF + ((v.u >> 16) & 1)) >> 16;
    return (short)r;
}
__device__ inline float bf2f(short h) {
    union { unsigned u; float f; } v;
    v.u = ((unsigned)(unsigned short)h) << 16;
    return v.f;
}

// ---------------- init: twiddle tables ----------------
// twA: bf16 [ (x*2+c) ][ d ]  (A-operand for DFT MFMA): c==0 -> cos, c==1 -> -sin
__global__ void k_init(short* __restrict__ twA, float* __restrict__ ct, float* __restrict__ st) {
    int idx = blockIdx.x * 256 + threadIdx.x;
    if (idx < 8192) {
        int n = idx >> 7, d = idx & 127;
        int x = n >> 1, c = n & 1;
        float ang = (float)((x * d) & 127) * 0.04908738521234052f; // 2*pi/128
        twA[idx] = f2bf((c == 0) ? cosf(ang) : -sinf(ang));
    }
    if (idx < 128) {
        float ang = (float)idx * 0.04908738521234052f;
        ct[idx] = cosf(ang);
        st[idx] = sinf(ang);
    }
}

// ---------------- weight transposes (both layers) ----------------
__global__ void k_wt(const float* __restrict__ xw, const float* __restrict__ dw,
                     const float* __restrict__ Kr, const float* __restrict__ Ki,
                     float* __restrict__ xwT, float* __restrict__ dwT,
                     float* __restrict__ ktr, float* __restrict__ kti) {
    int idx = blockIdx.x * 256 + threadIdx.x;
    if (idx < 2 * 128 * 80) {           // xwT[li][d][80]
        int li = idx / 10240, rem = idx % 10240, d = rem / 80, t = rem % 80;
        xwT[idx] = (t < 72) ? xw[li * 9216 + t * 128 + d] : 0.f;
    }
    if (idx < 2 * 8 * 128) {            // dwT[li][r][128]
        int li = idx / 1024, rem = idx % 1024, r = rem / 128, d = rem % 128;
        dwT[idx] = dw[li * 1024 + d * 8 + r];
    }
    if (idx < 2 * 32 * 32 * 32) {       // ktr/kti [li][x][o][i] (compact 8KB per x)
        int li = idx >> 15, rem = idx & 32767;
        int x = rem >> 10, o = (rem >> 5) & 31, i = rem & 31;
        int src = ((li * 32 + i) * 32 + o) * 32 + x;
        ktr[idx] = Kr[src];
        kti[idx] = Ki[src];
    }
}

// ---------------- per-(b,c) mean/std over T ----------------
__global__ void k_stats(const float* __restrict__ x, float* __restrict__ means, float* __restrict__ stdev) {
    int bc = blockIdx.x;
    int b = bc >> 5, c = bc & 31;
    int t = threadIdx.x; // 256
    float s1 = 0.f, s2 = 0.f;
    for (int tt = t; tt < 512; tt += 256) {
        float v = x[(b * 512 + tt) * 32 + c];
        s1 += v; s2 += v * v;
    }
    #pragma unroll
    for (int off = 32; off > 0; off >>= 1) {
        s1 += __shfl_xor(s1, off);
        s2 += __shfl_xor(s2, off);
    }
    __shared__ float r1[4], r2[4];
    int wave = t >> 6, lane = t & 63;
    if (lane == 0) { r1[wave] = s1; r2[wave] = s2; }
    __syncthreads();
    if (t == 0) {
        float S1 = r1[0] + r1[1] + r1[2] + r1[3];
        float S2 = r2[0] + r2[1] + r2[2] + r2[3];
        float mu = S1 * (1.f / 512.f);
        float var = S2 * (1.f / 512.f) - mu * mu;
        means[bc] = mu;
        stdev[bc] = sqrtf(var + 1e-5f);
    }
}

// ---------------- PSR embedding ----------------
__global__ void k_embed(const float* __restrict__ x, const float* __restrict__ means,
                        const float* __restrict__ stdev, float* __restrict__ enc,
                        float* __restrict__ encT) {
    int idx = blockIdx.x * 256 + threadIdx.x; // < 1048576
    int bc = idx >> 12, rem = idx & 4095;
    int p = rem >> 7, dd = rem & 127;
    int m = dd >> 4, l = dd & 15;
    int b = bc >> 5, c = bc & 31;
    int t = p * 16 + l;
    float v = 0.f;
    if (t >= 7) v = (x[(b * 512 + (t - 7 + m)) * 32 + c] - means[bc]) / stdev[bc];
    enc[idx] = v;                               // [r=(bc*32+p)][d]
    encT[(dd * 32 + p) * 256 + bc] = v;         // [d][rp]
}

// ---------------- LayerNorm + projections (coalesced weights) ----------------
__global__ __launch_bounds__(128) void k_lnproj(const float* __restrict__ enc,
                         const float* __restrict__ xwT,  // [d][80]
                         const float* __restrict__ dwT,  // [r][128]
                         const float* __restrict__ db,   // (128)
                         const float* __restrict__ g, const float* __restrict__ bb,
                         float* __restrict__ xnT,        // [d][rp]
                         float* __restrict__ xnR,        // [rp][d]
                         float* __restrict__ deltaT,     // [rp][d]
                         float* __restrict__ BmT,        // [p][s][bc]
                         float* __restrict__ CmT) {      // [o][rp]
    int r = blockIdx.x;          // bc*32+p
    int bc = r >> 5, p = r & 31;
    int rp = p * 256 + bc;
    int t = threadIdx.x;         // 128
    __shared__ float xs[128];
    __shared__ float red[4];
    __shared__ float dr[8];
    float e = enc[r * 128 + t];
    float s1 = e, s2 = e * e;
    #pragma unroll
    for (int off = 32; off > 0; off >>= 1) {
        s1 += __shfl_xor(s1, off);
        s2 += __shfl_xor(s2, off);
    }
    if ((t & 63) == 0) { red[(t >> 6) * 2] = s1; red[(t >> 6) * 2 + 1] = s2; }
    __syncthreads();
    float mu = (red[0] + red[2]) * (1.f / 128.f);
    float var = (red[1] + red[3]) * (1.f / 128.f) - mu * mu;
    float inv = rsqrtf(var + 1e-5f);
    float v = (e - mu) * inv * g[t] + bb[t];
    xs[t] = v;
    xnT[(t * 32 + p) * 256 + bc] = v;
    xnR[rp * 128 + t] = v;
    __syncthreads();
    if (t < 80) {
        float acc = 0.f;
        const f4* xs4 = (const f4*)xs;
        #pragma unroll 8
        for (int dq = 0; dq < 32; dq++) {
            f4 xv = xs4[dq];                     // LDS broadcast (b128)
            const float* wp = xwT + dq * 320 + t;  // coalesced over lanes
            acc += xv[0] * wp[0] + xv[1] * wp[80] + xv[2] * wp[160] + xv[3] * wp[240];
        }
        if (t < 8) dr[t] = acc;
        else if (t < 40) BmT[(p * 32 + (t - 8)) * 256 + bc] = acc;
        else if (t < 72) CmT[(t - 40) * 8192 + rp] = acc;
    }
    __syncthreads();
    float a = db[t];
    #pragma unroll
    for (int rr = 0; rr < 8; rr++) a += dr[rr] * dwT[rr * 128 + t];  // coalesced
    float sp = fmaxf(a, 0.f) + log1pf(expf(-fabsf(a)));  // stable softplus
    deltaT[rp * 128 + t] = sp;
}

// ---------------- selective scan; 8 s-states per thread ----------------
__global__ __launch_bounds__(256) void k_scan(const float* __restrict__ deltaT,  // [rp][d]
                                              const float* __restrict__ xnR,     // [rp][d]
                                              const float* __restrict__ BmT,     // [p][s][bc]
                                              const float* __restrict__ Alog,
                                              short* __restrict__ hsA) {         // bf16 [rowA=(s,p,bc)][d]
    int sg = blockIdx.x >> 7;               // 4 groups of 8 s
    int bc0 = (blockIdx.x & 127) * 2;
    int t = threadIdx.x;
    int d = t & 127, bcl = t >> 7, bc = bc0 + bcl;
    int s0 = sg * 8;
    float A[8], h[8];
    #pragma unroll
    for (int j = 0; j < 8; j++) {
        A[j] = -__expf(Alog[d * 32 + s0 + j]);
        h[j] = 0.f;
    }
    for (int p = 0; p < 32; p++) {
        int rp = p * 256 + bc;
        float dl = deltaT[rp * 128 + d];
        float xv = xnR[rp * 128 + d];
        float dx = dl * xv;
        #pragma unroll
        for (int j = 0; j < 8; j++) {
            float bv = BmT[(p * 32 + s0 + j) * 256 + bc];   // 2 addrs/wave -> 1 txn
            h[j] = __expf(dl * A[j]) * h[j] + dx * bv;
            hsA[(((s0 + j) * 32 + p) * 256 + bc) * 128 + d] = f2bf(h[j]);
        }
    }
}

// ---------------- DFT via MFMA: xf[m=(x,c)][rowA] = tw[m][d] * hs[d][rowA] ----------------
__global__ __launch_bounds__(256) void k_dft(const short* __restrict__ hsA,
                                             const short* __restrict__ twA,
                                             short* __restrict__ xfh) {
    int wave = threadIdx.x >> 6, lane = threadIdx.x & 63;
    int l15 = lane & 15, q = lane >> 4;
    // A fragments (constant twiddles): A[m=l15][k=q*8+j]
    s8 afr[4][4];
    #pragma unroll
    for (int mt = 0; mt < 4; mt++)
        #pragma unroll
        for (int kt = 0; kt < 4; kt++)
            afr[mt][kt] = *(const s8*)(twA + (mt * 16 + l15) * 128 + kt * 32 + q * 8);
    int tile0 = (blockIdx.x * 4 + wave) * 4;   // 4 tiles of 16 rows per wave
    for (int j = 0; j < 4; j++) {
        int n0 = (tile0 + j) * 16;
        f4 acc0 = {0.f, 0.f, 0.f, 0.f}, acc1 = acc0, acc2 = acc0, acc3 = acc0;
        #pragma unroll
        for (int kt = 0; kt < 4; kt++) {
            // B[k=q*8+j][n=l15] from hsA[row][d]
            s8 b = *(const s8*)(hsA + (n0 + l15) * 128 + kt * 32 + q * 8);
            acc0 = __builtin_amdgcn_mfma_f32_16x16x32_bf16(afr[0][kt], b, acc0, 0, 0, 0);
            acc1 = __builtin_amdgcn_mfma_f32_16x16x32_bf16(afr[1][kt], b, acc1, 0, 0, 0);
            acc2 = __builtin_amdgcn_mfma_f32_16x16x32_bf16(afr[2][kt], b, acc2, 0, 0, 0);
            acc3 = __builtin_amdgcn_mfma_f32_16x16x32_bf16(afr[3][kt], b, acc3, 0, 0, 0);
        }
        // D[row=q*4+r][col=l15]
        #pragma unroll
        for (int r = 0; r < 4; r++) {
            xfh[(q * 4 + r) * 262144 + n0 + l15]      = f2bf(acc0[r]);
            xfh[(16 + q * 4 + r) * 262144 + n0 + l15] = f2bf(acc1[r]);
            xfh[(32 + q * 4 + r) * 262144 + n0 + l15] = f2bf(acc2[r]);
            xfh[(48 + q * 4 + r) * 262144 + n0 + l15] = f2bf(acc3[r]);
        }
    }
}

// ---------------- mode mixing: u = K·Cm (scalar weights in SGPRs), g = <xf, u> ----------------
__global__ __launch_bounds__(256) void k_mix(const short* __restrict__ xfh,  // bf16 [(x2c)*32+i][rp]
                                             const float* __restrict__ CmT,  // [o][rp]
                                             const float* __restrict__ ktr,  // [x][o][i]
                                             const float* __restrict__ kti,
                                             float* __restrict__ gbuf) {     // [x2c][rp]
    int x = blockIdx.x >> 5;
    int rp = (blockIdx.x & 31) * 256 + threadIdx.x;
    const float* kr = ktr + x * 1024;   // wave-uniform -> s_load bursts, K$-resident (8KB/x)
    const float* ki = kti + x * 1024;
    float ur[32], ui[32];
    #pragma unroll
    for (int i = 0; i < 32; i++) { ur[i] = 0.f; ui[i] = 0.f; }
    for (int o = 0; o < 32; o++) {
        float co = CmT[o * 8192 + rp];
        const float* kro = kr + o * 32;
        const float* kio = ki + o * 32;
        #pragma unroll
        for (int i = 0; i < 32; i++) {
            ur[i] = fmaf(co, kro[i], ur[i]);   // v_fmac_f32 v, s, v
            ui[i] = fmaf(co, kio[i], ui[i]);
        }
    }
    float gr = 0.f, gi = 0.f;
    #pragma unroll
    for (int i = 0; i < 32; i++) {
        float xr = bf2f(xfh[((x * 2 + 0) * 32 + i) * 8192 + rp]);
        float xi = bf2f(xfh[((x * 2 + 1) * 32 + i) * 8192 + rp]);
        gr += xr * ur[i] - xi * ui[i];
        gi += xr * ui[i] + xi * ur[i];
    }
    gbuf[(x * 2 + 0) * 8192 + rp] = gr;
    gbuf[(x * 2 + 1) * 8192 + rp] = gi;
}

// ---------------- irfft + D-skip + residual ----------------
__global__ __launch_bounds__(256) void k_inv(const float* __restrict__ gbuf,
                                             const float* __restrict__ ct,
                                             const float* __restrict__ st,
                                             const float* __restrict__ Dp,
                                             const float* __restrict__ xnT,
                                             float* __restrict__ encT,
                                             float* __restrict__ enc) {
    int d = blockIdx.x >> 5;
    int rp = (blockIdx.x & 31) * 256 + threadIdx.x;
    float acc = gbuf[rp];   // Re(g[0]); imag of DC dropped (C2R convention)
    for (int x = 1; x < 32; x++) {
        int k = (x * d) & 127;
        float c = ct[k], s = st[k];
        acc += 2.f * (gbuf[(x * 2) * 8192 + rp] * c - gbuf[(x * 2 + 1) * 8192 + rp] * s);
    }
    float ys = acc * (1.f / 128.f);
    float v = ys + Dp[d] * xnT[d * 8192 + rp] + encT[d * 8192 + rp];
    encT[d * 8192 + rp] = v;
    int bc = rp & 255, p = rp >> 8;
    enc[(bc * 32 + p) * 128 + d] = v;
}

// ---------------- head: ow transpose ----------------
__global__ void k_trans(const float* __restrict__ ow, float* __restrict__ owT) {
    int idx = blockIdx.x * 256 + threadIdx.x;  // < 786432
    int k = idx / 192, t = idx - k * 192;
    owT[idx] = ow[t * 4096 + k];               // owT[k][t]
}

// ---------------- head: K-split GEMM partials ----------------
__global__ __launch_bounds__(192) void k_head(const float* __restrict__ enc,
                                              const float* __restrict__ owT,
                                              float* __restrict__ pbuf) {
    int bcg = blockIdx.x >> 4;
    int kc  = blockIdx.x & 15;
    int t = threadIdx.x;
    int bc0 = bcg * 16, kk0 = kc * 256;
    __shared__ float el[256 * 20];
    for (int u = t; u < 4096; u += 192) {
        int b = u >> 8, kl = u & 255;
        el[kl * 20 + b] = enc[(bc0 + b) * 4096 + kk0 + kl];
    }
    __syncthreads();
    float acc[16];
    #pragma unroll
    for (int b = 0; b < 16; b++) acc[b] = 0.f;
    for (int kl = 0; kl < 256; kl++) {
        float w = owT[(kk0 + kl) * 192 + t];
        const f4* e4 = (const f4*)(el + kl * 20);
        #pragma unroll
        for (int q = 0; q < 4; q++) {
            f4 e = e4[q];
            acc[q * 4 + 0] += w * e[0];
            acc[q * 4 + 1] += w * e[1];
            acc[q * 4 + 2] += w * e[2];
            acc[q * 4 + 3] += w * e[3];
        }
    }
    #pragma unroll
    for (int b = 0; b < 16; b++)
        pbuf[(kc * 256 + bc0 + b) * 192 + t] = acc[b];
}

// ---------------- head: reduce partials + epilogue ----------------
__global__ void k_headred(const float* __restrict__ pbuf, const float* __restrict__ ob,
                          const float* __restrict__ stdev, const float* __restrict__ means,
                          float* __restrict__ out) {
    int idx = blockIdx.x * 256 + threadIdx.x;  // < 49152
    int bc = idx / 192, t = idx - bc * 192;
    float s = 0.f;
    #pragma unroll
    for (int kc = 0; kc < 16; kc++) s += pbuf[kc * 49152 + idx];
    int b = bc >> 5, c = bc & 31;
    out[(b * PREDq + t) * 32 + c] = (s + ob[t]) * stdev[bc] + means[bc];
}

extern "C" void kernel_launch(void* const* d_in, const int* in_sizes, int n_in,
                              void* d_out, int out_size, void* d_ws, size_t ws_size,
                              hipStream_t stream) {
    const float* x     = (const float*)d_in[0];
    const float* xproj = (const float*)d_in[4];
    const float* dtw   = (const float*)d_in[5];
    const float* dtb   = (const float*)d_in[6];
    const float* Alog  = (const float*)d_in[7];
    const float* Dp    = (const float*)d_in[8];
    const float* Kr    = (const float*)d_in[9];
    const float* Ki    = (const float*)d_in[10];
    const float* lng   = (const float*)d_in[11];
    const float* lnb   = (const float*)d_in[12];
    const float* ow    = (const float*)d_in[13];
    const float* ob    = (const float*)d_in[14];
    float* out = (float*)d_out;

    float* w = (float*)d_ws;
    float* means  = w; w += 256;
    float* stdev  = w; w += 256;
    short* twA    = (short*)w; w += 4096;   // 8192 bf16
    float* ct     = w; w += 128;
    float* st     = w; w += 128;
    float* xwT    = w; w += 20480;     // [li][d][80]
    float* dwT    = w; w += 2048;      // [li][r][128]
    float* ktr    = w; w += 65536;     // [li][x][o][i]
    float* kti    = w; w += 65536;
    float* enc    = w; w += 1048576;   // [r][d]
    float* encT   = w; w += 1048576;   // [d][rp]
    float* xnT    = w; w += 1048576;   // [d][rp]
    float* xnR    = w; w += 1048576;   // [rp][d]
    float* deltaT = w; w += 1048576;   // [rp][d]
    float* BmT    = w; w += 262144;    // [p][s][bc]
    float* CmT    = w; w += 262144;    // [o][rp]
    float* gbuf   = w; w += 524288;    // [x2c][rp]
    short* xfh    = (short*)w; w += 8388608;   // bf16 [(x2c)*32+i][rp]
    short* hsA    = (short*)w; w += 8388608;   // bf16 [rowA=(s,p,bc)][d]
    // head scratch aliases xfh region (dead after last k_mix)
    float* owT  = (float*)xfh;         // 786432 floats
    float* pbuf = ((float*)xfh) + 786432;

    k_init<<<33, 256, 0, stream>>>(twA, ct, st);
    k_wt<<<256, 256, 0, stream>>>(xproj, dtw, Kr, Ki, xwT, dwT, ktr, kti);
    k_stats<<<256, 256, 0, stream>>>(x, means, stdev);
    k_embed<<<4096, 256, 0, stream>>>(x, means, stdev, enc, encT);
    for (int li = 0; li < 2; li++) {
        k_lnproj<<<8192, 128, 0, stream>>>(enc, xwT + li * 10240, dwT + li * 1024,
                                           dtb + li * 128, lng + li * 128, lnb + li * 128,
                                           xnT, xnR, deltaT, BmT, CmT);
        k_scan<<<512, 256, 0, stream>>>(deltaT, xnR, BmT, Alog + li * 4096, hsA);
        k_dft<<<1024, 256, 0, stream>>>(hsA, twA, xfh);
        k_mix<<<1024, 256, 0, stream>>>(xfh, CmT, ktr + li * 32768, kti + li * 32768, gbuf);
        k_inv<<<4096, 256, 0, stream>>>(gbuf, ct, st, Dp + li * 128, xnT, encT, enc);
    }
    k_trans<<<3072, 256, 0, stream>>>(ow, owT);
    k_head<<<256, 192, 0, stream>>>(enc, owT, pbuf);
    k_headred<<<192, 256, 0, stream>>>(pbuf, ob, stdev, means, out);
}

// Round 7
// 392.616 us; speedup vs baseline: 1.6691x; 1.0097x over previous
//
#include <hip/hip_runtime.h>

typedef __attribute__((ext_vector_type(8))) short s8;
typedef __attribute__((ext_vector_type(4))) float f4;

#define PREDq 192

__device__ inline short f2bf(float f) {
    union { float f; unsigned u; } v; v.f = f;
    unsigned r = (v.u + 0x7FFF + ((v.u >> 16) & 1)) >> 16;
    return (short)r;
}
__device__ inline float bf2f(short h) {
    union { unsigned u; float f; } v;
    v.u = ((unsigned)(unsigned short)h) << 16;
    return v.f;
}

// ---------------- fused setup: twiddles + weight transposes + ow->bf16 ----------------
__global__ void k_prep(const float* __restrict__ xw, const float* __restrict__ dw,
                       const float* __restrict__ Kr, const float* __restrict__ Ki,
                       const float* __restrict__ ow,
                       short* __restrict__ twA, float* __restrict__ ct, float* __restrict__ st,
                       float* __restrict__ xwT, float* __restrict__ dwT,
                       float* __restrict__ ktr, float* __restrict__ kti,
                       short* __restrict__ owh) {
    int idx = blockIdx.x * 256 + threadIdx.x;
    if (idx < 8192) {                   // twA bf16 [(x*2+c)][d]: c==0 cos, c==1 -sin
        int n = idx >> 7, d = idx & 127;
        int x = n >> 1, c = n & 1;
        float ang = (float)((x * d) & 127) * 0.04908738521234052f; // 2*pi/128
        twA[idx] = f2bf((c == 0) ? cosf(ang) : -sinf(ang));
    }
    if (idx < 128) {
        float ang = (float)idx * 0.04908738521234052f;
        ct[idx] = cosf(ang);
        st[idx] = sinf(ang);
    }
    if (idx < 2 * 128 * 80) {           // xwT[li][d][80]
        int li = idx / 10240, rem = idx % 10240, d = rem / 80, t = rem % 80;
        xwT[idx] = (t < 72) ? xw[li * 9216 + t * 128 + d] : 0.f;
    }
    if (idx < 2 * 8 * 128) {            // dwT[li][r][128]
        int li = idx / 1024, rem = idx % 1024, r = rem / 128, d = rem % 128;
        dwT[idx] = dw[li * 1024 + d * 8 + r];
    }
    if (idx < 2 * 32 * 32 * 32) {       // ktr/kti [li][x][o][i]
        int li = idx >> 15, rem = idx & 32767;
        int x = rem >> 10, o = (rem >> 5) & 31, i = rem & 31;
        int src = ((li * 32 + i) * 32 + o) * 32 + x;
        ktr[idx] = Kr[src];
        kti[idx] = Ki[src];
    }
    if (idx < 192 * 4096) {             // owh bf16, native [t][k]
        owh[idx] = f2bf(ow[idx]);
    }
}

// ---------------- per-(b,c) mean/std over T ----------------
__global__ void k_stats(const float* __restrict__ x, float* __restrict__ means, float* __restrict__ stdev) {
    int bc = blockIdx.x;
    int b = bc >> 5, c = bc & 31;
    int t = threadIdx.x; // 256
    float s1 = 0.f, s2 = 0.f;
    for (int tt = t; tt < 512; tt += 256) {
        float v = x[(b * 512 + tt) * 32 + c];
        s1 += v; s2 += v * v;
    }
    #pragma unroll
    for (int off = 32; off > 0; off >>= 1) {
        s1 += __shfl_xor(s1, off);
        s2 += __shfl_xor(s2, off);
    }
    __shared__ float r1[4], r2[4];
    int wave = t >> 6, lane = t & 63;
    if (lane == 0) { r1[wave] = s1; r2[wave] = s2; }
    __syncthreads();
    if (t == 0) {
        float S1 = r1[0] + r1[1] + r1[2] + r1[3];
        float S2 = r2[0] + r2[1] + r2[2] + r2[3];
        float mu = S1 * (1.f / 512.f);
        float var = S2 * (1.f / 512.f) - mu * mu;
        means[bc] = mu;
        stdev[bc] = sqrtf(var + 1e-5f);
    }
}

// ---------------- PSR embedding (coalesced enc only) ----------------
__global__ void k_embed(const float* __restrict__ x, const float* __restrict__ means,
                        const float* __restrict__ stdev, float* __restrict__ enc) {
    int idx = blockIdx.x * 256 + threadIdx.x; // < 1048576
    int bc = idx >> 12, rem = idx & 4095;
    int p = rem >> 7, dd = rem & 127;
    int m = dd >> 4, l = dd & 15;
    int b = bc >> 5, c = bc & 31;
    int t = p * 16 + l;
    float v = 0.f;
    if (t >= 7) v = (x[(b * 512 + (t - 7 + m)) * 32 + c] - means[bc]) / stdev[bc];
    enc[idx] = v;                               // [r=(bc*32+p)][d]
}

// ---------------- LayerNorm + projections (coalesced weights, no scattered stores) ----------------
__global__ __launch_bounds__(128) void k_lnproj(const float* __restrict__ enc,
                         const float* __restrict__ xwT,  // [d][80]
                         const float* __restrict__ dwT,  // [r][128]
                         const float* __restrict__ db,   // (128)
                         const float* __restrict__ g, const float* __restrict__ bb,
                         float* __restrict__ xnR,        // [rp][d]
                         float* __restrict__ deltaT,     // [rp][d]
                         float* __restrict__ BmR,        // [rp][s]
                         float* __restrict__ CmT) {      // [o][rp]
    int r = blockIdx.x;          // bc*32+p
    int bc = r >> 5, p = r & 31;
    int rp = p * 256 + bc;
    int t = threadIdx.x;         // 128
    __shared__ float xs[128];
    __shared__ float red[4];
    __shared__ float dr[8];
    float e = enc[r * 128 + t];
    float s1 = e, s2 = e * e;
    #pragma unroll
    for (int off = 32; off > 0; off >>= 1) {
        s1 += __shfl_xor(s1, off);
        s2 += __shfl_xor(s2, off);
    }
    if ((t & 63) == 0) { red[(t >> 6) * 2] = s1; red[(t >> 6) * 2 + 1] = s2; }
    __syncthreads();
    float mu = (red[0] + red[2]) * (1.f / 128.f);
    float var = (red[1] + red[3]) * (1.f / 128.f) - mu * mu;
    float inv = rsqrtf(var + 1e-5f);
    float v = (e - mu) * inv * g[t] + bb[t];
    xs[t] = v;
    xnR[rp * 128 + t] = v;
    __syncthreads();
    if (t < 80) {
        float acc = 0.f;
        const f4* xs4 = (const f4*)xs;
        #pragma unroll 8
        for (int dq = 0; dq < 32; dq++) {
            f4 xv = xs4[dq];                     // LDS broadcast (b128)
            const float* wp = xwT + dq * 320 + t;  // coalesced over lanes
            acc += xv[0] * wp[0] + xv[1] * wp[80] + xv[2] * wp[160] + xv[3] * wp[240];
        }
        if (t < 8) dr[t] = acc;
        else if (t < 40) BmR[rp * 32 + (t - 8)] = acc;      // coalesced
        else if (t < 72) CmT[(t - 40) * 8192 + rp] = acc;   // 32 sector stores (small)
    }
    __syncthreads();
    float a = db[t];
    #pragma unroll
    for (int rr = 0; rr < 8; rr++) a += dr[rr] * dwT[rr * 128 + t];  // coalesced
    float sp = fmaxf(a, 0.f) + log1pf(expf(-fabsf(a)));  // stable softplus
    deltaT[rp * 128 + t] = sp;
}

// ---------------- selective scan; 8 s-states per thread ----------------
__global__ __launch_bounds__(256) void k_scan(const float* __restrict__ deltaT,  // [rp][d]
                                              const float* __restrict__ xnR,     // [rp][d]
                                              const float* __restrict__ BmR,     // [rp][s]
                                              const float* __restrict__ Alog,
                                              short* __restrict__ hsA) {         // bf16 [rowA=(s,p,bc)][d]
    int sg = blockIdx.x >> 7;               // 4 groups of 8 s
    int bc0 = (blockIdx.x & 127) * 2;
    int t = threadIdx.x;
    int d = t & 127, bcl = t >> 7, bc = bc0 + bcl;
    int s0 = sg * 8;
    float A[8], h[8];
    #pragma unroll
    for (int j = 0; j < 8; j++) {
        A[j] = -__expf(Alog[d * 32 + s0 + j]);
        h[j] = 0.f;
    }
    for (int p = 0; p < 32; p++) {
        int rp = p * 256 + bc;
        float dl = deltaT[rp * 128 + d];
        float xv = xnR[rp * 128 + d];
        float dx = dl * xv;
        const f4* bp = (const f4*)(BmR + rp * 32 + s0);   // wave-uniform -> broadcast
        f4 b0 = bp[0], b1 = bp[1];
        #pragma unroll
        for (int j = 0; j < 4; j++) {
            h[j] = __expf(dl * A[j]) * h[j] + dx * b0[j];
            hsA[(((s0 + j) * 32 + p) * 256 + bc) * 128 + d] = f2bf(h[j]);
        }
        #pragma unroll
        for (int j = 0; j < 4; j++) {
            h[4 + j] = __expf(dl * A[4 + j]) * h[4 + j] + dx * b1[j];
            hsA[(((s0 + 4 + j) * 32 + p) * 256 + bc) * 128 + d] = f2bf(h[4 + j]);
        }
    }
}

// ---------------- DFT via MFMA: xf[m=(x,c)][rowA] = tw[m][d] * hs[d][rowA] ----------------
__global__ __launch_bounds__(256) void k_dft(const short* __restrict__ hsA,
                                             const short* __restrict__ twA,
                                             short* __restrict__ xfh) {
    int wave = threadIdx.x >> 6, lane = threadIdx.x & 63;
    int l15 = lane & 15, q = lane >> 4;
    // A fragments (constant twiddles): A[m=l15][k=q*8+j]
    s8 afr[4][4];
    #pragma unroll
    for (int mt = 0; mt < 4; mt++)
        #pragma unroll
        for (int kt = 0; kt < 4; kt++)
            afr[mt][kt] = *(const s8*)(twA + (mt * 16 + l15) * 128 + kt * 32 + q * 8);
    int tile0 = (blockIdx.x * 4 + wave) * 4;   // 4 tiles of 16 rows per wave
    for (int j = 0; j < 4; j++) {
        int n0 = (tile0 + j) * 16;
        f4 acc0 = {0.f, 0.f, 0.f, 0.f}, acc1 = acc0, acc2 = acc0, acc3 = acc0;
        #pragma unroll
        for (int kt = 0; kt < 4; kt++) {
            s8 b = *(const s8*)(hsA + (n0 + l15) * 128 + kt * 32 + q * 8);
            acc0 = __builtin_amdgcn_mfma_f32_16x16x32_bf16(afr[0][kt], b, acc0, 0, 0, 0);
            acc1 = __builtin_amdgcn_mfma_f32_16x16x32_bf16(afr[1][kt], b, acc1, 0, 0, 0);
            acc2 = __builtin_amdgcn_mfma_f32_16x16x32_bf16(afr[2][kt], b, acc2, 0, 0, 0);
            acc3 = __builtin_amdgcn_mfma_f32_16x16x32_bf16(afr[3][kt], b, acc3, 0, 0, 0);
        }
        // D[row=q*4+r][col=l15]
        #pragma unroll
        for (int r = 0; r < 4; r++) {
            xfh[(q * 4 + r) * 262144 + n0 + l15]      = f2bf(acc0[r]);
            xfh[(16 + q * 4 + r) * 262144 + n0 + l15] = f2bf(acc1[r]);
            xfh[(32 + q * 4 + r) * 262144 + n0 + l15] = f2bf(acc2[r]);
            xfh[(48 + q * 4 + r) * 262144 + n0 + l15] = f2bf(acc3[r]);
        }
    }
}

// ---------------- mode mixing: u = K·Cm (SGPR weights), g = <xf, u> ----------------
__global__ __launch_bounds__(256) void k_mix(const short* __restrict__ xfh,  // bf16 [(x2c)*32+i][rp]
                                             const float* __restrict__ CmT,  // [o][rp]
                                             const float* __restrict__ ktr,  // [x][o][i]
                                             const float* __restrict__ kti,
                                             float* __restrict__ gbuf) {     // [x2c][rp]
    int x = blockIdx.x >> 5;
    int rp = (blockIdx.x & 31) * 256 + threadIdx.x;
    const float* kr = ktr + x * 1024;   // wave-uniform -> s_load bursts
    const float* ki = kti + x * 1024;
    float ur[32], ui[32];
    #pragma unroll
    for (int i = 0; i < 32; i++) { ur[i] = 0.f; ui[i] = 0.f; }
    for (int o = 0; o < 32; o++) {
        float co = CmT[o * 8192 + rp];
        const float* kro = kr + o * 32;
        const float* kio = ki + o * 32;
        #pragma unroll
        for (int i = 0; i < 32; i++) {
            ur[i] = fmaf(co, kro[i], ur[i]);
            ui[i] = fmaf(co, kio[i], ui[i]);
        }
    }
    float gr = 0.f, gi = 0.f;
    #pragma unroll
    for (int i = 0; i < 32; i++) {
        float xr = bf2f(xfh[((x * 2 + 0) * 32 + i) * 8192 + rp]);
        float xi = bf2f(xfh[((x * 2 + 1) * 32 + i) * 8192 + rp]);
        gr += xr * ur[i] - xi * ui[i];
        gi += xr * ui[i] + xi * ur[i];
    }
    gbuf[(x * 2 + 0) * 8192 + rp] = gr;
    gbuf[(x * 2 + 1) * 8192 + rp] = gi;
}

// ---------------- irfft + D-skip + residual (coalesced over d) ----------------
__global__ __launch_bounds__(256) void k_inv(const float* __restrict__ gbuf,
                                             const float* __restrict__ ct,
                                             const float* __restrict__ st,
                                             const float* __restrict__ Dp,
                                             const float* __restrict__ xnR,
                                             float* __restrict__ enc,
                                             short* __restrict__ ench) {
    int t = threadIdx.x;
    int d = t & 127;
    int rp = blockIdx.x * 2 + (t >> 7);
    int bc = rp & 255, p = rp >> 8;
    int r = bc * 32 + p;
    float acc = gbuf[rp];   // Re(g[0]); imag of DC dropped (C2R convention)
    for (int x = 1; x < 32; x++) {
        int k = (x * d) & 127;
        float c = ct[k], s = st[k];  // gather within 512B tables (L1-hot)
        acc += 2.f * (gbuf[(x * 2) * 8192 + rp] * c - gbuf[(x * 2 + 1) * 8192 + rp] * s);
    }
    float ys = acc * (1.f / 128.f);
    float v = ys + Dp[d] * xnR[rp * 128 + d] + enc[r * 128 + d];
    enc[r * 128 + d] = v;
    ench[r * 128 + d] = f2bf(v);
}

// ---------------- head via MFMA: out[t][bc] = ow[t][:] . ench[bc][:] ----------------
__global__ __launch_bounds__(256) void k_head(const short* __restrict__ ench,  // [bc][4096]
                                              const short* __restrict__ owh,   // [t][4096]
                                              const float* __restrict__ ob,
                                              const float* __restrict__ stdev,
                                              const float* __restrict__ means,
                                              float* __restrict__ out) {
    int mt = blockIdx.x / 16;          // 12 t-tiles
    int nt = blockIdx.x % 16;          // 16 bc-tiles
    int wave = threadIdx.x >> 6, lane = threadIdx.x & 63;
    int l15 = lane & 15, q = lane >> 4;
    const short* aBase = owh + (mt * 16 + l15) * 4096;    // A[m=t][k]
    const short* bBase = ench + (nt * 16 + l15) * 4096;   // B[k][n=bc] from [n][k] rows
    f4 acc = {0.f, 0.f, 0.f, 0.f};
    for (int kc = wave * 32; kc < wave * 32 + 32; kc++) {  // K-split over 4 waves
        s8 a = *(const s8*)(aBase + kc * 32 + q * 8);
        s8 b = *(const s8*)(bBase + kc * 32 + q * 8);
        acc = __builtin_amdgcn_mfma_f32_16x16x32_bf16(a, b, acc, 0, 0, 0);
    }
    __shared__ float red[4][256];
    #pragma unroll
    for (int r = 0; r < 4; r++) red[wave][(q * 4 + r) * 16 + l15] = acc[r];
    __syncthreads();
    int tl = threadIdx.x;              // 256 = 16 m x 16 n
    float v = red[0][tl] + red[1][tl] + red[2][tl] + red[3][tl];
    int tt = mt * 16 + (tl >> 4);
    int bc = nt * 16 + (tl & 15);
    int b = bc >> 5, c = bc & 31;
    out[(b * PREDq + tt) * 32 + c] = (v + ob[tt]) * stdev[bc] + means[bc];
}

extern "C" void kernel_launch(void* const* d_in, const int* in_sizes, int n_in,
                              void* d_out, int out_size, void* d_ws, size_t ws_size,
                              hipStream_t stream) {
    const float* x     = (const float*)d_in[0];
    const float* xproj = (const float*)d_in[4];
    const float* dtw   = (const float*)d_in[5];
    const float* dtb   = (const float*)d_in[6];
    const float* Alog  = (const float*)d_in[7];
    const float* Dp    = (const float*)d_in[8];
    const float* Kr    = (const float*)d_in[9];
    const float* Ki    = (const float*)d_in[10];
    const float* lng   = (const float*)d_in[11];
    const float* lnb   = (const float*)d_in[12];
    const float* ow    = (const float*)d_in[13];
    const float* ob    = (const float*)d_in[14];
    float* out = (float*)d_out;

    float* w = (float*)d_ws;
    float* means  = w; w += 256;
    float* stdev  = w; w += 256;
    short* twA    = (short*)w; w += 4096;
    float* ct     = w; w += 128;
    float* st     = w; w += 128;
    float* xwT    = w; w += 20480;     // [li][d][80]
    float* dwT    = w; w += 2048;      // [li][r][128]
    float* ktr    = w; w += 65536;     // [li][x][o][i]
    float* kti    = w; w += 65536;
    float* enc    = w; w += 1048576;   // [r][d]
    float* xnR    = w; w += 1048576;   // [rp][d]
    float* deltaT = w; w += 1048576;   // [rp][d]
    float* BmR    = w; w += 262144;    // [rp][s]
    float* CmT    = w; w += 262144;    // [o][rp]
    float* gbuf   = w; w += 524288;    // [x2c][rp]
    short* ench   = (short*)w; w += 524288;    // bf16 [bc][4096]  (1,048,576 shorts)
    short* owh    = (short*)w; w += 393216;    // bf16 [t][4096]   (786,432 shorts)
    short* xfh    = (short*)w; w += 8388608;   // bf16 [(x2c)*32+i][rp]  (16,777,216 shorts)
    short* hsA    = (short*)w; w += 16777216;  // bf16 [rowA=(s,p,bc)][d] (33,554,432 shorts) -- FIXED SIZE

    k_prep<<<3072, 256, 0, stream>>>(xproj, dtw, Kr, Ki, ow,
                                     twA, ct, st, xwT, dwT, ktr, kti, owh);
    k_stats<<<256, 256, 0, stream>>>(x, means, stdev);
    k_embed<<<4096, 256, 0, stream>>>(x, means, stdev, enc);
    for (int li = 0; li < 2; li++) {
        k_lnproj<<<8192, 128, 0, stream>>>(enc, xwT + li * 10240, dwT + li * 1024,
                                           dtb + li * 128, lng + li * 128, lnb + li * 128,
                                           xnR, deltaT, BmR, CmT);
        k_scan<<<512, 256, 0, stream>>>(deltaT, xnR, BmR, Alog + li * 4096, hsA);
        k_dft<<<1024, 256, 0, stream>>>(hsA, twA, xfh);
        k_mix<<<1024, 256, 0, stream>>>(xfh, CmT, ktr + li * 32768, kti + li * 32768, gbuf);
        k_inv<<<4096, 256, 0, stream>>>(gbuf, ct, st, Dp + li * 128, xnR, enc, ench);
    }
    k_head<<<192, 256, 0, stream>>>(ench, owh, ob, stdev, means, out);
}

// Round 8
// 366.667 us; speedup vs baseline: 1.7872x; 1.0708x over previous
//
#include <hip/hip_runtime.h>

typedef __attribute__((ext_vector_type(8))) short s8;
typedef __attribute__((ext_vector_type(4))) float f4;

#define PREDq 192

__device__ inline short f2bf(float f) {
    union { float f; unsigned u; } v; v.f = f;
    unsigned r = (v.u + 0x7FFF + ((v.u >> 16) & 1)) >> 16;
    return (short)r;
}
__device__ inline float bf2f(short h) {
    union { unsigned u; float f; } v;
    v.u = ((unsigned)(unsigned short)h) << 16;
    return v.f;
}

// ---------------- fused setup: twiddles + weight transposes + ow->bf16 ----------------
__global__ void k_prep(const float* __restrict__ xw, const float* __restrict__ dw,
                       const float* __restrict__ Kr, const float* __restrict__ Ki,
                       const float* __restrict__ ow,
                       short* __restrict__ twA,
                       float* __restrict__ xwT, float* __restrict__ dwT,
                       float* __restrict__ ktr, float* __restrict__ kti,
                       short* __restrict__ owh) {
    int idx = blockIdx.x * 256 + threadIdx.x;
    if (idx < 8192) {                   // twA bf16 [(x*2+c)][d]: c==0 cos, c==1 -sin
        int n = idx >> 7, d = idx & 127;
        int x = n >> 1, c = n & 1;
        float ang = (float)((x * d) & 127) * 0.04908738521234052f; // 2*pi/128
        twA[idx] = f2bf((c == 0) ? cosf(ang) : -sinf(ang));
    }
    if (idx < 2 * 128 * 80) {           // xwT[li][d][80]
        int li = idx / 10240, rem = idx % 10240, d = rem / 80, t = rem % 80;
        xwT[idx] = (t < 72) ? xw[li * 9216 + t * 128 + d] : 0.f;
    }
    if (idx < 2 * 8 * 128) {            // dwT[li][r][128]
        int li = idx / 1024, rem = idx % 1024, r = rem / 128, d = rem % 128;
        dwT[idx] = dw[li * 1024 + d * 8 + r];
    }
    if (idx < 2 * 32 * 32 * 32) {       // ktr/kti [li][x][o][i]
        int li = idx >> 15, rem = idx & 32767;
        int x = rem >> 10, o = (rem >> 5) & 31, i = rem & 31;
        int src = ((li * 32 + i) * 32 + o) * 32 + x;
        ktr[idx] = Kr[src];
        kti[idx] = Ki[src];
    }
    if (idx < 192 * 4096) {             // owh bf16, native [t][k]
        owh[idx] = f2bf(ow[idx]);
    }
}

// ---------------- per-(b,c) mean/std over T ----------------
__global__ void k_stats(const float* __restrict__ x, float* __restrict__ means, float* __restrict__ stdev) {
    int bc = blockIdx.x;
    int b = bc >> 5, c = bc & 31;
    int t = threadIdx.x; // 256
    float s1 = 0.f, s2 = 0.f;
    for (int tt = t; tt < 512; tt += 256) {
        float v = x[(b * 512 + tt) * 32 + c];
        s1 += v; s2 += v * v;
    }
    #pragma unroll
    for (int off = 32; off > 0; off >>= 1) {
        s1 += __shfl_xor(s1, off);
        s2 += __shfl_xor(s2, off);
    }
    __shared__ float r1[4], r2[4];
    int wave = t >> 6, lane = t & 63;
    if (lane == 0) { r1[wave] = s1; r2[wave] = s2; }
    __syncthreads();
    if (t == 0) {
        float S1 = r1[0] + r1[1] + r1[2] + r1[3];
        float S2 = r2[0] + r2[1] + r2[2] + r2[3];
        float mu = S1 * (1.f / 512.f);
        float var = S2 * (1.f / 512.f) - mu * mu;
        means[bc] = mu;
        stdev[bc] = sqrtf(var + 1e-5f);
    }
}

// ---------------- PSR embedding (coalesced enc only) ----------------
__global__ void k_embed(const float* __restrict__ x, const float* __restrict__ means,
                        const float* __restrict__ stdev, float* __restrict__ enc) {
    int idx = blockIdx.x * 256 + threadIdx.x; // < 1048576
    int bc = idx >> 12, rem = idx & 4095;
    int p = rem >> 7, dd = rem & 127;
    int m = dd >> 4, l = dd & 15;
    int b = bc >> 5, c = bc & 31;
    int t = p * 16 + l;
    float v = 0.f;
    if (t >= 7) v = (x[(b * 512 + (t - 7 + m)) * 32 + c] - means[bc]) / stdev[bc];
    enc[idx] = v;                               // [r=(bc*32+p)][d]
}

// ---------------- LayerNorm + projections (coalesced weights, no scattered stores) ----------------
__global__ __launch_bounds__(128) void k_lnproj(const float* __restrict__ enc,
                         const float* __restrict__ xwT,  // [d][80]
                         const float* __restrict__ dwT,  // [r][128]
                         const float* __restrict__ db,   // (128)
                         const float* __restrict__ g, const float* __restrict__ bb,
                         float* __restrict__ xnR,        // [rp][d]
                         float* __restrict__ deltaT,     // [rp][d]
                         float* __restrict__ BmR,        // [rp][s]
                         float* __restrict__ CmT) {      // [o][rp]
    int r = blockIdx.x;          // bc*32+p
    int bc = r >> 5, p = r & 31;
    int rp = p * 256 + bc;
    int t = threadIdx.x;         // 128
    __shared__ float xs[128];
    __shared__ float red[4];
    __shared__ float dr[8];
    float e = enc[r * 128 + t];
    float s1 = e, s2 = e * e;
    #pragma unroll
    for (int off = 32; off > 0; off >>= 1) {
        s1 += __shfl_xor(s1, off);
        s2 += __shfl_xor(s2, off);
    }
    if ((t & 63) == 0) { red[(t >> 6) * 2] = s1; red[(t >> 6) * 2 + 1] = s2; }
    __syncthreads();
    float mu = (red[0] + red[2]) * (1.f / 128.f);
    float var = (red[1] + red[3]) * (1.f / 128.f) - mu * mu;
    float inv = rsqrtf(var + 1e-5f);
    float v = (e - mu) * inv * g[t] + bb[t];
    xs[t] = v;
    xnR[rp * 128 + t] = v;
    __syncthreads();
    if (t < 80) {
        float acc = 0.f;
        const f4* xs4 = (const f4*)xs;
        #pragma unroll 8
        for (int dq = 0; dq < 32; dq++) {
            f4 xv = xs4[dq];                     // LDS broadcast (b128)
            const float* wp = xwT + dq * 320 + t;  // coalesced over lanes
            acc += xv[0] * wp[0] + xv[1] * wp[80] + xv[2] * wp[160] + xv[3] * wp[240];
        }
        if (t < 8) dr[t] = acc;
        else if (t < 40) BmR[rp * 32 + (t - 8)] = acc;      // coalesced
        else if (t < 72) CmT[(t - 40) * 8192 + rp] = acc;   // 32 sector stores (small)
    }
    __syncthreads();
    float a = db[t];
    #pragma unroll
    for (int rr = 0; rr < 8; rr++) a += dr[rr] * dwT[rr * 128 + t];  // coalesced
    float sp = fmaxf(a, 0.f) + log1pf(expf(-fabsf(a)));  // stable softplus
    deltaT[rp * 128 + t] = sp;
}

// ---------------- selective scan; 8 s-states per thread ----------------
__global__ __launch_bounds__(256) void k_scan(const float* __restrict__ deltaT,  // [rp][d]
                                              const float* __restrict__ xnR,     // [rp][d]
                                              const float* __restrict__ BmR,     // [rp][s]
                                              const float* __restrict__ Alog,
                                              short* __restrict__ hsA) {         // bf16 [rowA=(s,p,bc)][d]
    int sg = blockIdx.x >> 7;               // 4 groups of 8 s
    int bc0 = (blockIdx.x & 127) * 2;
    int t = threadIdx.x;
    int d = t & 127, bcl = t >> 7, bc = bc0 + bcl;
    int s0 = sg * 8;
    float A[8], h[8];
    #pragma unroll
    for (int j = 0; j < 8; j++) {
        A[j] = -__expf(Alog[d * 32 + s0 + j]);
        h[j] = 0.f;
    }
    for (int p = 0; p < 32; p++) {
        int rp = p * 256 + bc;
        float dl = deltaT[rp * 128 + d];
        float xv = xnR[rp * 128 + d];
        float dx = dl * xv;
        const f4* bp = (const f4*)(BmR + rp * 32 + s0);   // wave-uniform -> broadcast
        f4 b0 = bp[0], b1 = bp[1];
        #pragma unroll
        for (int j = 0; j < 4; j++) {
            h[j] = __expf(dl * A[j]) * h[j] + dx * b0[j];
            hsA[(((s0 + j) * 32 + p) * 256 + bc) * 128 + d] = f2bf(h[j]);
        }
        #pragma unroll
        for (int j = 0; j < 4; j++) {
            h[4 + j] = __expf(dl * A[4 + j]) * h[4 + j] + dx * b1[j];
            hsA[(((s0 + 4 + j) * 32 + p) * 256 + bc) * 128 + d] = f2bf(h[4 + j]);
        }
    }
}

// ---------------- DFT via MFMA: xf[m=(x,c)][rowA] = tw[m][d] * hs[d][rowA] ----------------
__global__ __launch_bounds__(256) void k_dft(const short* __restrict__ hsA,
                                             const short* __restrict__ twA,
                                             short* __restrict__ xfh) {
    int wave = threadIdx.x >> 6, lane = threadIdx.x & 63;
    int l15 = lane & 15, q = lane >> 4;
    // A fragments (constant twiddles): A[m=l15][k=q*8+j]
    s8 afr[4][4];
    #pragma unroll
    for (int mt = 0; mt < 4; mt++)
        #pragma unroll
        for (int kt = 0; kt < 4; kt++)
            afr[mt][kt] = *(const s8*)(twA + (mt * 16 + l15) * 128 + kt * 32 + q * 8);
    int tile0 = (blockIdx.x * 4 + wave) * 4;   // 4 tiles of 16 rows per wave
    for (int j = 0; j < 4; j++) {
        int n0 = (tile0 + j) * 16;
        f4 acc0 = {0.f, 0.f, 0.f, 0.f}, acc1 = acc0, acc2 = acc0, acc3 = acc0;
        #pragma unroll
        for (int kt = 0; kt < 4; kt++) {
            s8 b = *(const s8*)(hsA + (n0 + l15) * 128 + kt * 32 + q * 8);
            acc0 = __builtin_amdgcn_mfma_f32_16x16x32_bf16(afr[0][kt], b, acc0, 0, 0, 0);
            acc1 = __builtin_amdgcn_mfma_f32_16x16x32_bf16(afr[1][kt], b, acc1, 0, 0, 0);
            acc2 = __builtin_amdgcn_mfma_f32_16x16x32_bf16(afr[2][kt], b, acc2, 0, 0, 0);
            acc3 = __builtin_amdgcn_mfma_f32_16x16x32_bf16(afr[3][kt], b, acc3, 0, 0, 0);
        }
        // D[row=q*4+r][col=l15]
        #pragma unroll
        for (int r = 0; r < 4; r++) {
            xfh[(q * 4 + r) * 262144 + n0 + l15]      = f2bf(acc0[r]);
            xfh[(16 + q * 4 + r) * 262144 + n0 + l15] = f2bf(acc1[r]);
            xfh[(32 + q * 4 + r) * 262144 + n0 + l15] = f2bf(acc2[r]);
            xfh[(48 + q * 4 + r) * 262144 + n0 + l15] = f2bf(acc3[r]);
        }
    }
}

// ---------------- mode mixing: u = K·Cm (SGPR weights), g = <xf, u> ----------------
__global__ __launch_bounds__(256) void k_mix(const short* __restrict__ xfh,  // bf16 [(x2c)*32+i][rp]
                                             const float* __restrict__ CmT,  // [o][rp]
                                             const float* __restrict__ ktr,  // [x][o][i]
                                             const float* __restrict__ kti,
                                             float* __restrict__ gbuf) {     // [x2c][rp]
    int x = blockIdx.x >> 5;
    int rp = (blockIdx.x & 31) * 256 + threadIdx.x;
    const float* kr = ktr + x * 1024;   // wave-uniform -> s_load bursts
    const float* ki = kti + x * 1024;
    float ur[32], ui[32];
    #pragma unroll
    for (int i = 0; i < 32; i++) { ur[i] = 0.f; ui[i] = 0.f; }
    for (int o = 0; o < 32; o++) {
        float co = CmT[o * 8192 + rp];
        const float* kro = kr + o * 32;
        const float* kio = ki + o * 32;
        #pragma unroll
        for (int i = 0; i < 32; i++) {
            ur[i] = fmaf(co, kro[i], ur[i]);
            ui[i] = fmaf(co, kio[i], ui[i]);
        }
    }
    float gr = 0.f, gi = 0.f;
    #pragma unroll
    for (int i = 0; i < 32; i++) {
        float xr = bf2f(xfh[((x * 2 + 0) * 32 + i) * 8192 + rp]);
        float xi = bf2f(xfh[((x * 2 + 1) * 32 + i) * 8192 + rp]);
        gr += xr * ur[i] - xi * ui[i];
        gi += xr * ui[i] + xi * ur[i];
    }
    gbuf[(x * 2 + 0) * 8192 + rp] = gr;
    gbuf[(x * 2 + 1) * 8192 + rp] = gi;
}

// ---------------- irfft + D-skip + residual: block = rp, scalar gbuf, trig recurrence ----------------
__global__ __launch_bounds__(128) void k_inv(const float* __restrict__ gbuf,
                                             const float* __restrict__ Dp,
                                             const float* __restrict__ xnR,
                                             float* __restrict__ enc,
                                             short* __restrict__ ench) {
    int rp = blockIdx.x;               // uniform -> gbuf loads scalarize
    int d = threadIdx.x;               // 128
    int bc = rp & 255, p = rp >> 8;
    int r = bc * 32 + p;
    const float* gb = gbuf + rp;
    float ang = (float)d * 0.04908738521234052f;   // 2*pi*d/128
    float c1, s1;
    __sincosf(ang, &s1, &c1);
    float cx = c1, sx = s1;
    float acc = gb[0];                 // Re(g[0]); imag of DC dropped (C2R convention)
    #pragma unroll 4
    for (int x = 1; x < 32; x++) {
        float gr = gb[(2 * x) * 8192];
        float gi = gb[(2 * x + 1) * 8192];
        acc = fmaf(2.f * gr, cx, acc);
        acc = fmaf(-2.f * gi, sx, acc);
        float cn = cx * c1 - sx * s1;  // rotate to angle (x+1)*ang
        float sn = sx * c1 + cx * s1;
        cx = cn; sx = sn;
    }
    float ys = acc * (1.f / 128.f);
    float v = ys + Dp[d] * xnR[rp * 128 + d] + enc[r * 128 + d];
    enc[r * 128 + d] = v;
    ench[r * 128 + d] = f2bf(v);
}

// ---------------- head via MFMA: out[t][bc] = ow[t][:] . ench[bc][:] ----------------
__global__ __launch_bounds__(256) void k_head(const short* __restrict__ ench,  // [bc][4096]
                                              const short* __restrict__ owh,   // [t][4096]
                                              const float* __restrict__ ob,
                                              const float* __restrict__ stdev,
                                              const float* __restrict__ means,
                                              float* __restrict__ out) {
    int mt = blockIdx.x / 16;          // 12 t-tiles
    int nt = blockIdx.x % 16;          // 16 bc-tiles
    int wave = threadIdx.x >> 6, lane = threadIdx.x & 63;
    int l15 = lane & 15, q = lane >> 4;
    const short* aBase = owh + (mt * 16 + l15) * 4096;    // A[m=t][k]
    const short* bBase = ench + (nt * 16 + l15) * 4096;   // B[k][n=bc] from [n][k] rows
    f4 acc = {0.f, 0.f, 0.f, 0.f};
    for (int kc = wave * 32; kc < wave * 32 + 32; kc++) {  // K-split over 4 waves
        s8 a = *(const s8*)(aBase + kc * 32 + q * 8);
        s8 b = *(const s8*)(bBase + kc * 32 + q * 8);
        acc = __builtin_amdgcn_mfma_f32_16x16x32_bf16(a, b, acc, 0, 0, 0);
    }
    __shared__ float red[4][256];
    #pragma unroll
    for (int r = 0; r < 4; r++) red[wave][(q * 4 + r) * 16 + l15] = acc[r];
    __syncthreads();
    int tl = threadIdx.x;              // 256 = 16 m x 16 n
    float v = red[0][tl] + red[1][tl] + red[2][tl] + red[3][tl];
    int tt = mt * 16 + (tl >> 4);
    int bc = nt * 16 + (tl & 15);
    int b = bc >> 5, c = bc & 31;
    out[(b * PREDq + tt) * 32 + c] = (v + ob[tt]) * stdev[bc] + means[bc];
}

extern "C" void kernel_launch(void* const* d_in, const int* in_sizes, int n_in,
                              void* d_out, int out_size, void* d_ws, size_t ws_size,
                              hipStream_t stream) {
    const float* x     = (const float*)d_in[0];
    const float* xproj = (const float*)d_in[4];
    const float* dtw   = (const float*)d_in[5];
    const float* dtb   = (const float*)d_in[6];
    const float* Alog  = (const float*)d_in[7];
    const float* Dp    = (const float*)d_in[8];
    const float* Kr    = (const float*)d_in[9];
    const float* Ki    = (const float*)d_in[10];
    const float* lng   = (const float*)d_in[11];
    const float* lnb   = (const float*)d_in[12];
    const float* ow    = (const float*)d_in[13];
    const float* ob    = (const float*)d_in[14];
    float* out = (float*)d_out;

    float* w = (float*)d_ws;
    float* means  = w; w += 256;
    float* stdev  = w; w += 256;
    short* twA    = (short*)w; w += 4096;
    float* xwT    = w; w += 20480;     // [li][d][80]
    float* dwT    = w; w += 2048;      // [li][r][128]
    float* ktr    = w; w += 65536;     // [li][x][o][i]
    float* kti    = w; w += 65536;
    float* enc    = w; w += 1048576;   // [r][d]
    float* xnR    = w; w += 1048576;   // [rp][d]
    float* deltaT = w; w += 1048576;   // [rp][d]
    float* BmR    = w; w += 262144;    // [rp][s]
    float* CmT    = w; w += 262144;    // [o][rp]
    float* gbuf   = w; w += 524288;    // [x2c][rp]
    short* ench   = (short*)w; w += 524288;    // bf16 [bc][4096]
    short* owh    = (short*)w; w += 393216;    // bf16 [t][4096]
    short* xfh    = (short*)w; w += 8388608;   // bf16 [(x2c)*32+i][rp]
    short* hsA    = (short*)w; w += 16777216;  // bf16 [rowA=(s,p,bc)][d]

    k_prep<<<3072, 256, 0, stream>>>(xproj, dtw, Kr, Ki, ow,
                                     twA, xwT, dwT, ktr, kti, owh);
    k_stats<<<256, 256, 0, stream>>>(x, means, stdev);
    k_embed<<<4096, 256, 0, stream>>>(x, means, stdev, enc);
    for (int li = 0; li < 2; li++) {
        k_lnproj<<<8192, 128, 0, stream>>>(enc, xwT + li * 10240, dwT + li * 1024,
                                           dtb + li * 128, lng + li * 128, lnb + li * 128,
                                           xnR, deltaT, BmR, CmT);
        k_scan<<<512, 256, 0, stream>>>(deltaT, xnR, BmR, Alog + li * 4096, hsA);
        k_dft<<<1024, 256, 0, stream>>>(hsA, twA, xfh);
        k_mix<<<1024, 256, 0, stream>>>(xfh, CmT, ktr + li * 32768, kti + li * 32768, gbuf);
        k_inv<<<8192, 128, 0, stream>>>(gbuf, Dp + li * 128, xnR, enc, ench);
    }
    k_head<<<192, 256, 0, stream>>>(ench, owh, ob, stdev, means, out);
}

// Round 9
// 322.711 us; speedup vs baseline: 2.0306x; 1.1362x over previous
//
#include <hip/hip_runtime.h>

typedef __attribute__((ext_vector_type(8))) short s8;
typedef __attribute__((ext_vector_type(4))) float f4;

#define PREDq 192

__device__ inline short f2bf(float f) {
    union { float f; unsigned u; } v; v.f = f;
    unsigned r = (v.u + 0x7FFF + ((v.u >> 16) & 1)) >> 16;
    return (short)r;
}
__device__ inline float bf2f(short h) {
    union { unsigned u; float f; } v;
    v.u = ((unsigned)(unsigned short)h) << 16;
    return v.f;
}

// ---------------- fused setup: twiddles + weight transposes + ow->bf16 + stats ----------------
__global__ void k_prep(const float* __restrict__ xw, const float* __restrict__ dw,
                       const float* __restrict__ Kr, const float* __restrict__ Ki,
                       const float* __restrict__ ow, const float* __restrict__ x,
                       short* __restrict__ twA,
                       float* __restrict__ xwT, float* __restrict__ dwT,
                       float* __restrict__ ktr, float* __restrict__ kti,
                       short* __restrict__ owh,
                       float* __restrict__ means, float* __restrict__ stdev) {
    if (blockIdx.x >= 3072) {           // ---- stats blocks ----
        int bc = blockIdx.x - 3072;
        int b = bc >> 5, c = bc & 31;
        int t = threadIdx.x;
        float s1 = 0.f, s2 = 0.f;
        for (int tt = t; tt < 512; tt += 256) {
            float v = x[(b * 512 + tt) * 32 + c];
            s1 += v; s2 += v * v;
        }
        #pragma unroll
        for (int off = 32; off > 0; off >>= 1) {
            s1 += __shfl_xor(s1, off);
            s2 += __shfl_xor(s2, off);
        }
        __shared__ float r1[4], r2[4];
        int wave = t >> 6, lane = t & 63;
        if (lane == 0) { r1[wave] = s1; r2[wave] = s2; }
        __syncthreads();
        if (t == 0) {
            float S1 = r1[0] + r1[1] + r1[2] + r1[3];
            float S2 = r2[0] + r2[1] + r2[2] + r2[3];
            float mu = S1 * (1.f / 512.f);
            float var = S2 * (1.f / 512.f) - mu * mu;
            means[bc] = mu;
            stdev[bc] = sqrtf(var + 1e-5f);
        }
        return;
    }
    int idx = blockIdx.x * 256 + threadIdx.x;
    if (idx < 8192) {                   // twA bf16 [(x*2+c)][d]: c==0 cos, c==1 -sin
        int n = idx >> 7, d = idx & 127;
        int xx = n >> 1, c = n & 1;
        float ang = (float)((xx * d) & 127) * 0.04908738521234052f; // 2*pi/128
        twA[idx] = f2bf((c == 0) ? cosf(ang) : -sinf(ang));
    }
    if (idx < 2 * 128 * 80) {           // xwT[li][d][80]
        int li = idx / 10240, rem = idx % 10240, d = rem / 80, t = rem % 80;
        xwT[idx] = (t < 72) ? xw[li * 9216 + t * 128 + d] : 0.f;
    }
    if (idx < 2 * 8 * 128) {            // dwT[li][r][128]
        int li = idx / 1024, rem = idx % 1024, r = rem / 128, d = rem % 128;
        dwT[idx] = dw[li * 1024 + d * 8 + r];
    }
    if (idx < 2 * 32 * 32 * 32) {       // ktr/kti [li][x][o][i]
        int li = idx >> 15, rem = idx & 32767;
        int xx = rem >> 10, o = (rem >> 5) & 31, i = rem & 31;
        int src = ((li * 32 + i) * 32 + o) * 32 + xx;
        ktr[idx] = Kr[src];
        kti[idx] = Ki[src];
    }
    if (idx < 192 * 4096) {             // owh bf16, native [t][k]
        owh[idx] = f2bf(ow[idx]);
    }
}

// ---------------- PSR embedding (coalesced enc only) ----------------
__global__ void k_embed(const float* __restrict__ x, const float* __restrict__ means,
                        const float* __restrict__ stdev, float* __restrict__ enc) {
    int idx = blockIdx.x * 256 + threadIdx.x; // < 1048576
    int bc = idx >> 12, rem = idx & 4095;
    int p = rem >> 7, dd = rem & 127;
    int m = dd >> 4, l = dd & 15;
    int b = bc >> 5, c = bc & 31;
    int t = p * 16 + l;
    float v = 0.f;
    if (t >= 7) v = (x[(b * 512 + (t - 7 + m)) * 32 + c] - means[bc]) / stdev[bc];
    enc[idx] = v;                               // [r=(bc*32+p)][d]
}

// ---------------- LayerNorm + projections ----------------
__global__ __launch_bounds__(128) void k_lnproj(const float* __restrict__ enc,
                         const float* __restrict__ xwT,  // [d][80]
                         const float* __restrict__ dwT,  // [r][128]
                         const float* __restrict__ db,   // (128)
                         const float* __restrict__ g, const float* __restrict__ bb,
                         float* __restrict__ xnR,        // [rp][d]
                         float* __restrict__ deltaT,     // [rp][d]
                         float* __restrict__ BmR,        // [rp][s]
                         float* __restrict__ CmT) {      // [o][rp]
    int r = blockIdx.x;          // bc*32+p
    int bc = r >> 5, p = r & 31;
    int rp = p * 256 + bc;
    int t = threadIdx.x;         // 128
    __shared__ float xs[128];
    __shared__ float red[4];
    __shared__ float dr[8];
    float e = enc[r * 128 + t];
    float s1 = e, s2 = e * e;
    #pragma unroll
    for (int off = 32; off > 0; off >>= 1) {
        s1 += __shfl_xor(s1, off);
        s2 += __shfl_xor(s2, off);
    }
    if ((t & 63) == 0) { red[(t >> 6) * 2] = s1; red[(t >> 6) * 2 + 1] = s2; }
    __syncthreads();
    float mu = (red[0] + red[2]) * (1.f / 128.f);
    float var = (red[1] + red[3]) * (1.f / 128.f) - mu * mu;
    float inv = rsqrtf(var + 1e-5f);
    float v = (e - mu) * inv * g[t] + bb[t];
    xs[t] = v;
    xnR[rp * 128 + t] = v;
    __syncthreads();
    if (t < 80) {
        float acc = 0.f;
        const f4* xs4 = (const f4*)xs;
        #pragma unroll 8
        for (int dq = 0; dq < 32; dq++) {
            f4 xv = xs4[dq];
            const float* wp = xwT + dq * 320 + t;
            acc += xv[0] * wp[0] + xv[1] * wp[80] + xv[2] * wp[160] + xv[3] * wp[240];
        }
        if (t < 8) dr[t] = acc;
        else if (t < 40) BmR[rp * 32 + (t - 8)] = acc;
        else if (t < 72) CmT[(t - 40) * 8192 + rp] = acc;
    }
    __syncthreads();
    float a = db[t];
    #pragma unroll
    for (int rr = 0; rr < 8; rr++) a += dr[rr] * dwT[rr * 128 + t];
    float sp = fmaxf(a, 0.f) + log1pf(expf(-fabsf(a)));
    deltaT[rp * 128 + t] = sp;
}

// ---------------- fused scan + MFMA DFT (hsA eliminated) ----------------
// block = (bc, s-half): 128 threads = d lanes; per p: scan -> LDS (bf16, dbuf) -> MFMA
// xfh layout: [m=(x*2+c)][rp][s]  (m*262144 + rp*32 + s)
__global__ __launch_bounds__(128) void k_scandft(const float* __restrict__ deltaT,  // [rp][d]
                                                 const float* __restrict__ xnR,     // [rp][d]
                                                 const float* __restrict__ BmR,     // [rp][s]
                                                 const float* __restrict__ Alog,
                                                 const short* __restrict__ twA,
                                                 short* __restrict__ xfh) {
    int bc = blockIdx.x >> 1;
    int s0 = (blockIdx.x & 1) * 16;
    int t = threadIdx.x;
    int d = t;
    int wave = t >> 6, lane = t & 63, l15 = lane & 15, q = lane >> 4;
    __shared__ short lds[2][16 * 136];   // 16 rows x (128 + 8 pad) shorts, double-buffered

    // A fragments for this wave's 2 accsets: m rows (2*wave+aa)*16 + l15
    s8 afr[2][4];
    #pragma unroll
    for (int aa = 0; aa < 2; aa++)
        #pragma unroll
        for (int kt = 0; kt < 4; kt++)
            afr[aa][kt] = *(const s8*)(twA + ((wave * 2 + aa) * 16 + l15) * 128 + kt * 32 + q * 8);

    float A[16], h[16];
    #pragma unroll
    for (int j = 0; j < 16; j++) {
        A[j] = -__expf(Alog[d * 32 + s0 + j]);
        h[j] = 0.f;
    }

    const float* dptr = deltaT + bc * 128 + d;
    const float* xptr = xnR + bc * 128 + d;
    const f4*    bptr = (const f4*)(BmR + bc * 32 + s0);   // wave-uniform -> scalar

    float dl = dptr[0], xv = xptr[0];
    f4 b0 = bptr[0], b1 = bptr[1], b2 = bptr[2], b3 = bptr[3];

    for (int p = 0; p < 32; p++) {
        int pn = (p < 31) ? p + 1 : 31;
        float dln = dptr[pn * 32768];          // prefetch next p
        float xvn = xptr[pn * 32768];
        f4 nb0 = bptr[pn * 2048], nb1 = bptr[pn * 2048 + 1];
        f4 nb2 = bptr[pn * 2048 + 2], nb3 = bptr[pn * 2048 + 3];

        float dx = dl * xv;
        short* buf = &lds[p & 1][0];
        #pragma unroll
        for (int j = 0; j < 16; j++) {
            float bv = (j < 4) ? b0[j & 3] : (j < 8) ? b1[j & 3] : (j < 12) ? b2[j & 3] : b3[j & 3];
            h[j] = __expf(dl * A[j]) * h[j] + dx * bv;
            buf[j * 136 + d] = f2bf(h[j]);
        }
        __syncthreads();

        // DFT on this p's tile: 16 rows (s) x 128 (d) -> 64 modes
        int rp = p * 256 + bc;
        s8 bfr[4];
        #pragma unroll
        for (int kt = 0; kt < 4; kt++)
            bfr[kt] = *(const s8*)(buf + l15 * 136 + kt * 32 + q * 8);
        f4 acc0 = {0.f, 0.f, 0.f, 0.f}, acc1 = acc0;
        #pragma unroll
        for (int kt = 0; kt < 4; kt++) {
            acc0 = __builtin_amdgcn_mfma_f32_16x16x32_bf16(afr[0][kt], bfr[kt], acc0, 0, 0, 0);
            acc1 = __builtin_amdgcn_mfma_f32_16x16x32_bf16(afr[1][kt], bfr[kt], acc1, 0, 0, 0);
        }
        // D[row=q*4+r][col=l15]: m = (2*wave+aa)*16 + q*4 + r, col -> s = s0+l15
        #pragma unroll
        for (int r = 0; r < 4; r++) {
            int m0 = (wave * 2 + 0) * 16 + q * 4 + r;
            int m1 = (wave * 2 + 1) * 16 + q * 4 + r;
            xfh[m0 * 262144 + rp * 32 + s0 + l15] = f2bf(acc0[r]);
            xfh[m1 * 262144 + rp * 32 + s0 + l15] = f2bf(acc1[r]);
        }
        dl = dln; xv = xvn;
        b0 = nb0; b1 = nb1; b2 = nb2; b3 = nb3;
    }
}

// ---------------- mode mixing: u = K·Cm (SGPR weights), g = <xf, u> ----------------
__global__ __launch_bounds__(256) void k_mix(const short* __restrict__ xfh,  // [m][rp][s]
                                             const float* __restrict__ CmT,  // [o][rp]
                                             const float* __restrict__ ktr,  // [x][o][i]
                                             const float* __restrict__ kti,
                                             float* __restrict__ gbuf) {     // [x2c][rp]
    int x = blockIdx.x >> 5;
    int rp = (blockIdx.x & 31) * 256 + threadIdx.x;
    const float* kr = ktr + x * 1024;   // wave-uniform -> s_load bursts
    const float* ki = kti + x * 1024;
    float ur[32], ui[32];
    #pragma unroll
    for (int i = 0; i < 32; i++) { ur[i] = 0.f; ui[i] = 0.f; }
    for (int o = 0; o < 32; o++) {
        float co = CmT[o * 8192 + rp];
        const float* kro = kr + o * 32;
        const float* kio = ki + o * 32;
        #pragma unroll
        for (int i = 0; i < 32; i++) {
            ur[i] = fmaf(co, kro[i], ur[i]);
            ui[i] = fmaf(co, kio[i], ui[i]);
        }
    }
    const s8* pr = (const s8*)(xfh + (x * 2 + 0) * 262144 + rp * 32);  // 64B/lane contiguous
    const s8* pi = (const s8*)(xfh + (x * 2 + 1) * 262144 + rp * 32);
    s8 vr0 = pr[0], vr1 = pr[1], vr2 = pr[2], vr3 = pr[3];
    s8 vi0 = pi[0], vi1 = pi[1], vi2 = pi[2], vi3 = pi[3];
    float gr = 0.f, gi = 0.f;
    #pragma unroll
    for (int i = 0; i < 8; i++) {
        float xr, xi;
        xr = bf2f(vr0[i]); xi = bf2f(vi0[i]);
        gr += xr * ur[i] - xi * ui[i];      gi += xr * ui[i] + xi * ur[i];
        xr = bf2f(vr1[i]); xi = bf2f(vi1[i]);
        gr += xr * ur[8+i] - xi * ui[8+i];  gi += xr * ui[8+i] + xi * ur[8+i];
        xr = bf2f(vr2[i]); xi = bf2f(vi2[i]);
        gr += xr * ur[16+i] - xi * ui[16+i]; gi += xr * ui[16+i] + xi * ur[16+i];
        xr = bf2f(vr3[i]); xi = bf2f(vi3[i]);
        gr += xr * ur[24+i] - xi * ui[24+i]; gi += xr * ui[24+i] + xi * ur[24+i];
    }
    gbuf[(x * 2 + 0) * 8192 + rp] = gr;
    gbuf[(x * 2 + 1) * 8192 + rp] = gi;
}

// ---------------- irfft + D-skip + residual: block = rp, scalar gbuf, trig recurrence ----------------
__global__ __launch_bounds__(128) void k_inv(const float* __restrict__ gbuf,
                                             const float* __restrict__ Dp,
                                             const float* __restrict__ xnR,
                                             float* __restrict__ enc,
                                             short* __restrict__ ench,
                                             int wr_enc, int wr_ench) {
    int rp = blockIdx.x;               // uniform -> gbuf loads scalarize
    int d = threadIdx.x;               // 128
    int bc = rp & 255, p = rp >> 8;
    int r = bc * 32 + p;
    const float* gb = gbuf + rp;
    float ang = (float)d * 0.04908738521234052f;   // 2*pi*d/128
    float c1, s1;
    __sincosf(ang, &s1, &c1);
    float cx = c1, sx = s1;
    float acc = gb[0];
    #pragma unroll 4
    for (int x = 1; x < 32; x++) {
        float gr = gb[(2 * x) * 8192];
        float gi = gb[(2 * x + 1) * 8192];
        acc = fmaf(2.f * gr, cx, acc);
        acc = fmaf(-2.f * gi, sx, acc);
        float cn = cx * c1 - sx * s1;
        float sn = sx * c1 + cx * s1;
        cx = cn; sx = sn;
    }
    float ys = acc * (1.f / 128.f);
    float v = ys + Dp[d] * xnR[rp * 128 + d] + enc[r * 128 + d];
    if (wr_enc)  enc[r * 128 + d] = v;
    if (wr_ench) ench[r * 128 + d] = f2bf(v);
}

// ---------------- head via MFMA: out[t][bc] = ow[t][:] . ench[bc][:] ----------------
__global__ __launch_bounds__(256) void k_head(const short* __restrict__ ench,  // [bc][4096]
                                              const short* __restrict__ owh,   // [t][4096]
                                              const float* __restrict__ ob,
                                              const float* __restrict__ stdev,
                                              const float* __restrict__ means,
                                              float* __restrict__ out) {
    int mt = blockIdx.x / 16;
    int nt = blockIdx.x % 16;
    int wave = threadIdx.x >> 6, lane = threadIdx.x & 63;
    int l15 = lane & 15, q = lane >> 4;
    const short* aBase = owh + (mt * 16 + l15) * 4096;
    const short* bBase = ench + (nt * 16 + l15) * 4096;
    f4 acc = {0.f, 0.f, 0.f, 0.f};
    for (int kc = wave * 32; kc < wave * 32 + 32; kc++) {
        s8 a = *(const s8*)(aBase + kc * 32 + q * 8);
        s8 b = *(const s8*)(bBase + kc * 32 + q * 8);
        acc = __builtin_amdgcn_mfma_f32_16x16x32_bf16(a, b, acc, 0, 0, 0);
    }
    __shared__ float red[4][256];
    #pragma unroll
    for (int r = 0; r < 4; r++) red[wave][(q * 4 + r) * 16 + l15] = acc[r];
    __syncthreads();
    int tl = threadIdx.x;
    float v = red[0][tl] + red[1][tl] + red[2][tl] + red[3][tl];
    int tt = mt * 16 + (tl >> 4);
    int bc = nt * 16 + (tl & 15);
    int b = bc >> 5, c = bc & 31;
    out[(b * PREDq + tt) * 32 + c] = (v + ob[tt]) * stdev[bc] + means[bc];
}

extern "C" void kernel_launch(void* const* d_in, const int* in_sizes, int n_in,
                              void* d_out, int out_size, void* d_ws, size_t ws_size,
                              hipStream_t stream) {
    const float* x     = (const float*)d_in[0];
    const float* xproj = (const float*)d_in[4];
    const float* dtw   = (const float*)d_in[5];
    const float* dtb   = (const float*)d_in[6];
    const float* Alog  = (const float*)d_in[7];
    const float* Dp    = (const float*)d_in[8];
    const float* Kr    = (const float*)d_in[9];
    const float* Ki    = (const float*)d_in[10];
    const float* lng   = (const float*)d_in[11];
    const float* lnb   = (const float*)d_in[12];
    const float* ow    = (const float*)d_in[13];
    const float* ob    = (const float*)d_in[14];
    float* out = (float*)d_out;

    float* w = (float*)d_ws;
    float* means  = w; w += 256;
    float* stdev  = w; w += 256;
    short* twA    = (short*)w; w += 4096;
    float* xwT    = w; w += 20480;     // [li][d][80]
    float* dwT    = w; w += 2048;      // [li][r][128]
    float* ktr    = w; w += 65536;     // [li][x][o][i]
    float* kti    = w; w += 65536;
    float* enc    = w; w += 1048576;   // [r][d]
    float* xnR    = w; w += 1048576;   // [rp][d]
    float* deltaT = w; w += 1048576;   // [rp][d]
    float* BmR    = w; w += 262144;    // [rp][s]
    float* CmT    = w; w += 262144;    // [o][rp]
    float* gbuf   = w; w += 524288;    // [x2c][rp]
    short* ench   = (short*)w; w += 524288;    // bf16 [bc][4096]
    short* owh    = (short*)w; w += 393216;    // bf16 [t][4096]
    short* xfh    = (short*)w; w += 8388608;   // bf16 [m][rp][s]  (16,777,216 shorts)

    k_prep<<<3328, 256, 0, stream>>>(xproj, dtw, Kr, Ki, ow, x,
                                     twA, xwT, dwT, ktr, kti, owh, means, stdev);
    k_embed<<<4096, 256, 0, stream>>>(x, means, stdev, enc);
    for (int li = 0; li < 2; li++) {
        k_lnproj<<<8192, 128, 0, stream>>>(enc, xwT + li * 10240, dwT + li * 1024,
                                           dtb + li * 128, lng + li * 128, lnb + li * 128,
                                           xnR, deltaT, BmR, CmT);
        k_scandft<<<512, 128, 0, stream>>>(deltaT, xnR, BmR, Alog + li * 4096, twA, xfh);
        k_mix<<<1024, 256, 0, stream>>>(xfh, CmT, ktr + li * 32768, kti + li * 32768, gbuf);
        k_inv<<<8192, 128, 0, stream>>>(gbuf, Dp + li * 128, xnR, enc, ench,
                                        (li == 0) ? 1 : 0, (li == 1) ? 1 : 0);
    }
    k_head<<<192, 256, 0, stream>>>(ench, owh, ob, stdev, means, out);
}

// Round 10
// 320.781 us; speedup vs baseline: 2.0429x; 1.0060x over previous
//
#include <hip/hip_runtime.h>

typedef __attribute__((ext_vector_type(8))) short s8;
typedef __attribute__((ext_vector_type(4))) float f4;

#define PREDq 192

__device__ inline short f2bf(float f) {
    union { float f; unsigned u; } v; v.f = f;
    unsigned r = (v.u + 0x7FFF + ((v.u >> 16) & 1)) >> 16;
    return (short)r;
}
__device__ inline float bf2f(short h) {
    union { unsigned u; float f; } v;
    v.u = ((unsigned)(unsigned short)h) << 16;
    return v.f;
}

// ---------------- fused setup: twiddles + weight transposes + ow->bf16 + stats ----------------
__global__ void k_prep(const float* __restrict__ xw, const float* __restrict__ dw,
                       const float* __restrict__ Kr, const float* __restrict__ Ki,
                       const float* __restrict__ ow, const float* __restrict__ x,
                       short* __restrict__ twA,
                       float* __restrict__ xwT, float* __restrict__ dwT,
                       float* __restrict__ ktr, float* __restrict__ kti,
                       short* __restrict__ owh,
                       float* __restrict__ means, float* __restrict__ stdev) {
    if (blockIdx.x >= 3072) {           // ---- stats blocks ----
        int bc = blockIdx.x - 3072;
        int b = bc >> 5, c = bc & 31;
        int t = threadIdx.x;
        float s1 = 0.f, s2 = 0.f;
        for (int tt = t; tt < 512; tt += 256) {
            float v = x[(b * 512 + tt) * 32 + c];
            s1 += v; s2 += v * v;
        }
        #pragma unroll
        for (int off = 32; off > 0; off >>= 1) {
            s1 += __shfl_xor(s1, off);
            s2 += __shfl_xor(s2, off);
        }
        __shared__ float r1[4], r2[4];
        int wave = t >> 6, lane = t & 63;
        if (lane == 0) { r1[wave] = s1; r2[wave] = s2; }
        __syncthreads();
        if (t == 0) {
            float S1 = r1[0] + r1[1] + r1[2] + r1[3];
            float S2 = r2[0] + r2[1] + r2[2] + r2[3];
            float mu = S1 * (1.f / 512.f);
            float var = S2 * (1.f / 512.f) - mu * mu;
            means[bc] = mu;
            stdev[bc] = sqrtf(var + 1e-5f);
        }
        return;
    }
    int idx = blockIdx.x * 256 + threadIdx.x;
    if (idx < 8192) {                   // twA bf16 [(x*2+c)][d]: c==0 cos, c==1 -sin
        int n = idx >> 7, d = idx & 127;
        int xx = n >> 1, c = n & 1;
        float ang = (float)((xx * d) & 127) * 0.04908738521234052f; // 2*pi/128
        twA[idx] = f2bf((c == 0) ? cosf(ang) : -sinf(ang));
    }
    if (idx < 2 * 128 * 80) {           // xwT[li][d][80]
        int li = idx / 10240, rem = idx % 10240, d = rem / 80, t = rem % 80;
        xwT[idx] = (t < 72) ? xw[li * 9216 + t * 128 + d] : 0.f;
    }
    if (idx < 2 * 8 * 128) {            // dwT[li][r][128]
        int li = idx / 1024, rem = idx % 1024, r = rem / 128, d = rem % 128;
        dwT[idx] = dw[li * 1024 + d * 8 + r];
    }
    if (idx < 2 * 32 * 32 * 32) {       // ktr/kti [li][x][o][i]
        int li = idx >> 15, rem = idx & 32767;
        int xx = rem >> 10, o = (rem >> 5) & 31, i = rem & 31;
        int src = ((li * 32 + i) * 32 + o) * 32 + xx;
        ktr[idx] = Kr[src];
        kti[idx] = Ki[src];
    }
    if (idx < 192 * 4096) {             // owh bf16, native [t][k]
        owh[idx] = f2bf(ow[idx]);
    }
}

// ---------------- PSR embedding (coalesced enc only) ----------------
__global__ void k_embed(const float* __restrict__ x, const float* __restrict__ means,
                        const float* __restrict__ stdev, float* __restrict__ enc) {
    int idx = blockIdx.x * 256 + threadIdx.x; // < 1048576
    int bc = idx >> 12, rem = idx & 4095;
    int p = rem >> 7, dd = rem & 127;
    int m = dd >> 4, l = dd & 15;
    int b = bc >> 5, c = bc & 31;
    int t = p * 16 + l;
    float v = 0.f;
    if (t >= 7) v = (x[(b * 512 + (t - 7 + m)) * 32 + c] - means[bc]) / stdev[bc];
    enc[idx] = v;                               // [r=(bc*32+p)][d]
}

// ---------------- LayerNorm + projections ----------------
__global__ __launch_bounds__(128) void k_lnproj(const float* __restrict__ enc,
                         const float* __restrict__ xwT,  // [d][80]
                         const float* __restrict__ dwT,  // [r][128]
                         const float* __restrict__ db,   // (128)
                         const float* __restrict__ g, const float* __restrict__ bb,
                         float* __restrict__ xnR,        // [rp][d]
                         float* __restrict__ deltaT,     // [rp][d]
                         float* __restrict__ BmR,        // [rp][s]
                         float* __restrict__ CmT) {      // [o][rp]
    int r = blockIdx.x;          // bc*32+p
    int bc = r >> 5, p = r & 31;
    int rp = p * 256 + bc;
    int t = threadIdx.x;         // 128
    __shared__ float xs[128];
    __shared__ float red[4];
    __shared__ float dr[8];
    float e = enc[r * 128 + t];
    float s1 = e, s2 = e * e;
    #pragma unroll
    for (int off = 32; off > 0; off >>= 1) {
        s1 += __shfl_xor(s1, off);
        s2 += __shfl_xor(s2, off);
    }
    if ((t & 63) == 0) { red[(t >> 6) * 2] = s1; red[(t >> 6) * 2 + 1] = s2; }
    __syncthreads();
    float mu = (red[0] + red[2]) * (1.f / 128.f);
    float var = (red[1] + red[3]) * (1.f / 128.f) - mu * mu;
    float inv = rsqrtf(var + 1e-5f);
    float v = (e - mu) * inv * g[t] + bb[t];
    xs[t] = v;
    xnR[rp * 128 + t] = v;
    __syncthreads();
    if (t < 80) {
        float acc = 0.f;
        const f4* xs4 = (const f4*)xs;
        #pragma unroll 8
        for (int dq = 0; dq < 32; dq++) {
            f4 xv = xs4[dq];
            const float* wp = xwT + dq * 320 + t;
            acc += xv[0] * wp[0] + xv[1] * wp[80] + xv[2] * wp[160] + xv[3] * wp[240];
        }
        if (t < 8) dr[t] = acc;
        else if (t < 40) BmR[rp * 32 + (t - 8)] = acc;
        else if (t < 72) CmT[(t - 40) * 8192 + rp] = acc;
    }
    __syncthreads();
    float a = db[t];
    #pragma unroll
    for (int rr = 0; rr < 8; rr++) a += dr[rr] * dwT[rr * 128 + t];
    float sp = fmaxf(a, 0.f) + log1pf(expf(-fabsf(a)));
    deltaT[rp * 128 + t] = sp;
}

// ---------------- fused scan + MFMA DFT, wave-autonomous (no barriers) ----------------
// 1 wave per (bc, s-half). lane = (q = lane>>4, l15 = lane&15); lane holds h for
// d = kt*32 + q*8 + j (kt=0..3, j=0..7) at s = s0 + l15  == MFMA B-fragment layout.
// xfh layout: [m=(x*2+c)][rp][s]
__global__ __launch_bounds__(64) void k_scandft(const float* __restrict__ deltaT,  // [rp][d]
                                                const float* __restrict__ xnR,     // [rp][d]
                                                const float* __restrict__ BmR,     // [rp][s]
                                                const float* __restrict__ Alog,
                                                const short* __restrict__ twA,
                                                short* __restrict__ xfh) {
    int bc = blockIdx.x >> 1;
    int s0 = (blockIdx.x & 1) * 16;
    int lane = threadIdx.x;
    int l15 = lane & 15, q = lane >> 4;
    int s = s0 + l15;

    __shared__ float dlb[2][128];
    __shared__ float xvb[2][128];

    // twiddle A-fragments: 4 m-tiles x 4 kt (one-time)
    s8 afr[4][4];
    #pragma unroll
    for (int mt = 0; mt < 4; mt++)
        #pragma unroll
        for (int kt = 0; kt < 4; kt++)
            afr[mt][kt] = *(const s8*)(twA + (mt * 16 + l15) * 128 + kt * 32 + q * 8);

    // scan decay per state (one-time scattered loads)
    float A[4][8], h[4][8];
    #pragma unroll
    for (int kt = 0; kt < 4; kt++)
        #pragma unroll
        for (int j = 0; j < 8; j++) {
            int d = kt * 32 + q * 8 + j;
            A[kt][j] = -__expf(Alog[d * 32 + s]);
            h[kt][j] = 0.f;
        }

    const float2* dp2 = (const float2*)deltaT;
    const float2* xp2 = (const float2*)xnR;
    int rbase = bc * 64 + lane;            // float2 index of row element
    int bvbase = bc * 32 + s;

    // stage p=0
    {
        float2 dv = dp2[rbase];
        float2 xv = xp2[rbase];
        ((float2*)&dlb[0][0])[lane] = dv;
        ((float2*)&xvb[0][0])[lane] = xv;
    }
    float bvc = BmR[bvbase];

    for (int p = 0; p < 32; p++) {
        int buf = p & 1;
        // prefetch next p (global)
        float2 dnxt, xnxt; float bvn = 0.f;
        if (p < 31) {
            dnxt = dp2[(p + 1) * 16384 + rbase];
            xnxt = xp2[(p + 1) * 16384 + rbase];
            bvn  = BmR[(p + 1) * 8192 + bvbase];
        }
        // scan update + pack B fragments from registers
        s8 bfr[4];
        #pragma unroll
        for (int kt = 0; kt < 4; kt++) {
            f4 dl0 = *(const f4*)(&dlb[buf][kt * 32 + q * 8]);      // quad-broadcast b128
            f4 dl1 = *(const f4*)(&dlb[buf][kt * 32 + q * 8 + 4]);
            f4 xv0 = *(const f4*)(&xvb[buf][kt * 32 + q * 8]);
            f4 xv1 = *(const f4*)(&xvb[buf][kt * 32 + q * 8 + 4]);
            #pragma unroll
            for (int j = 0; j < 4; j++) {
                float dl = dl0[j], xv = xv0[j];
                h[kt][j] = __expf(dl * A[kt][j]) * h[kt][j] + dl * xv * bvc;
            }
            #pragma unroll
            for (int j = 0; j < 4; j++) {
                float dl = dl1[j], xv = xv1[j];
                h[kt][4 + j] = __expf(dl * A[kt][4 + j]) * h[kt][4 + j] + dl * xv * bvc;
            }
            union { int i[4]; s8 v; } u;
            #pragma unroll
            for (int t2 = 0; t2 < 4; t2++) {
                int lo = __float_as_int(h[kt][2 * t2]);
                int hi = __float_as_int(h[kt][2 * t2 + 1]);
                u.i[t2] = __builtin_amdgcn_perm(hi, lo, 0x07060302);  // [hi.hi16 | lo.hi16]
            }
            bfr[kt] = u.v;
        }
        // stage next p into alternate LDS buffer (wave-local, no barrier)
        if (p < 31) {
            ((float2*)&dlb[buf ^ 1][0])[lane] = dnxt;
            ((float2*)&xvb[buf ^ 1][0])[lane] = xnxt;
            bvc = bvn;
        }
        // MFMA: 4 m-tiles of 16 modes
        f4 acc0 = {0.f, 0.f, 0.f, 0.f}, acc1 = acc0, acc2 = acc0, acc3 = acc0;
        #pragma unroll
        for (int kt = 0; kt < 4; kt++) {
            acc0 = __builtin_amdgcn_mfma_f32_16x16x32_bf16(afr[0][kt], bfr[kt], acc0, 0, 0, 0);
            acc1 = __builtin_amdgcn_mfma_f32_16x16x32_bf16(afr[1][kt], bfr[kt], acc1, 0, 0, 0);
            acc2 = __builtin_amdgcn_mfma_f32_16x16x32_bf16(afr[2][kt], bfr[kt], acc2, 0, 0, 0);
            acc3 = __builtin_amdgcn_mfma_f32_16x16x32_bf16(afr[3][kt], bfr[kt], acc3, 0, 0, 0);
        }
        // D[row=q*4+r][col=l15] -> m = mt*16 + q*4 + r
        int rp = p * 256 + bc;
        long ob = (long)rp * 32 + s;
        #pragma unroll
        for (int r = 0; r < 4; r++) {
            int m = q * 4 + r;
            xfh[(m +  0) * 262144 + ob] = (short)(__float_as_int(acc0[r]) >> 16);
            xfh[(m + 16) * 262144 + ob] = (short)(__float_as_int(acc1[r]) >> 16);
            xfh[(m + 32) * 262144 + ob] = (short)(__float_as_int(acc2[r]) >> 16);
            xfh[(m + 48) * 262144 + ob] = (short)(__float_as_int(acc3[r]) >> 16);
        }
    }
}

// ---------------- mode mixing: u = K·Cm (SGPR weights), g = <xf, u> ----------------
__global__ __launch_bounds__(256) void k_mix(const short* __restrict__ xfh,  // [m][rp][s]
                                             const float* __restrict__ CmT,  // [o][rp]
                                             const float* __restrict__ ktr,  // [x][o][i]
                                             const float* __restrict__ kti,
                                             float* __restrict__ gbuf) {     // [x2c][rp]
    int x = blockIdx.x >> 5;
    int rp = (blockIdx.x & 31) * 256 + threadIdx.x;
    const float* kr = ktr + x * 1024;   // wave-uniform -> s_load bursts
    const float* ki = kti + x * 1024;
    float ur[32], ui[32];
    #pragma unroll
    for (int i = 0; i < 32; i++) { ur[i] = 0.f; ui[i] = 0.f; }
    for (int o = 0; o < 32; o++) {
        float co = CmT[o * 8192 + rp];
        const float* kro = kr + o * 32;
        const float* kio = ki + o * 32;
        #pragma unroll
        for (int i = 0; i < 32; i++) {
            ur[i] = fmaf(co, kro[i], ur[i]);
            ui[i] = fmaf(co, kio[i], ui[i]);
        }
    }
    const s8* pr = (const s8*)(xfh + (x * 2 + 0) * 262144 + rp * 32);  // 64B/lane contiguous
    const s8* pi = (const s8*)(xfh + (x * 2 + 1) * 262144 + rp * 32);
    s8 vr0 = pr[0], vr1 = pr[1], vr2 = pr[2], vr3 = pr[3];
    s8 vi0 = pi[0], vi1 = pi[1], vi2 = pi[2], vi3 = pi[3];
    float gr = 0.f, gi = 0.f;
    #pragma unroll
    for (int i = 0; i < 8; i++) {
        float xr, xi;
        xr = bf2f(vr0[i]); xi = bf2f(vi0[i]);
        gr += xr * ur[i] - xi * ui[i];      gi += xr * ui[i] + xi * ur[i];
        xr = bf2f(vr1[i]); xi = bf2f(vi1[i]);
        gr += xr * ur[8+i] - xi * ui[8+i];  gi += xr * ui[8+i] + xi * ur[8+i];
        xr = bf2f(vr2[i]); xi = bf2f(vi2[i]);
        gr += xr * ur[16+i] - xi * ui[16+i]; gi += xr * ui[16+i] + xi * ur[16+i];
        xr = bf2f(vr3[i]); xi = bf2f(vi3[i]);
        gr += xr * ur[24+i] - xi * ui[24+i]; gi += xr * ui[24+i] + xi * ur[24+i];
    }
    gbuf[(x * 2 + 0) * 8192 + rp] = gr;
    gbuf[(x * 2 + 1) * 8192 + rp] = gi;
}

// ---------------- irfft + D-skip + residual: block = rp, scalar gbuf, trig recurrence ----------------
__global__ __launch_bounds__(128) void k_inv(const float* __restrict__ gbuf,
                                             const float* __restrict__ Dp,
                                             const float* __restrict__ xnR,
                                             float* __restrict__ enc,
                                             short* __restrict__ ench,
                                             int wr_enc, int wr_ench) {
    int rp = blockIdx.x;               // uniform -> gbuf loads scalarize
    int d = threadIdx.x;               // 128
    int bc = rp & 255, p = rp >> 8;
    int r = bc * 32 + p;
    const float* gb = gbuf + rp;
    float ang = (float)d * 0.04908738521234052f;   // 2*pi*d/128
    float c1, s1;
    __sincosf(ang, &s1, &c1);
    float cx = c1, sx = s1;
    float acc = gb[0];
    #pragma unroll 4
    for (int x = 1; x < 32; x++) {
        float gr = gb[(2 * x) * 8192];
        float gi = gb[(2 * x + 1) * 8192];
        acc = fmaf(2.f * gr, cx, acc);
        acc = fmaf(-2.f * gi, sx, acc);
        float cn = cx * c1 - sx * s1;
        float sn = sx * c1 + cx * s1;
        cx = cn; sx = sn;
    }
    float ys = acc * (1.f / 128.f);
    float v = ys + Dp[d] * xnR[rp * 128 + d] + enc[r * 128 + d];
    if (wr_enc)  enc[r * 128 + d] = v;
    if (wr_ench) ench[r * 128 + d] = f2bf(v);
}

// ---------------- head via MFMA: out[t][bc] = ow[t][:] . ench[bc][:] ----------------
__global__ __launch_bounds__(256) void k_head(const short* __restrict__ ench,  // [bc][4096]
                                              const short* __restrict__ owh,   // [t][4096]
                                              const float* __restrict__ ob,
                                              const float* __restrict__ stdev,
                                              const float* __restrict__ means,
                                              float* __restrict__ out) {
    int mt = blockIdx.x / 16;
    int nt = blockIdx.x % 16;
    int wave = threadIdx.x >> 6, lane = threadIdx.x & 63;
    int l15 = lane & 15, q = lane >> 4;
    const short* aBase = owh + (mt * 16 + l15) * 4096;
    const short* bBase = ench + (nt * 16 + l15) * 4096;
    f4 acc = {0.f, 0.f, 0.f, 0.f};
    for (int kc = wave * 32; kc < wave * 32 + 32; kc++) {
        s8 a = *(const s8*)(aBase + kc * 32 + q * 8);
        s8 b = *(const s8*)(bBase + kc * 32 + q * 8);
        acc = __builtin_amdgcn_mfma_f32_16x16x32_bf16(a, b, acc, 0, 0, 0);
    }
    __shared__ float red[4][256];
    #pragma unroll
    for (int r = 0; r < 4; r++) red[wave][(q * 4 + r) * 16 + l15] = acc[r];
    __syncthreads();
    int tl = threadIdx.x;
    float v = red[0][tl] + red[1][tl] + red[2][tl] + red[3][tl];
    int tt = mt * 16 + (tl >> 4);
    int bc = nt * 16 + (tl & 15);
    int b = bc >> 5, c = bc & 31;
    out[(b * PREDq + tt) * 32 + c] = (v + ob[tt]) * stdev[bc] + means[bc];
}

extern "C" void kernel_launch(void* const* d_in, const int* in_sizes, int n_in,
                              void* d_out, int out_size, void* d_ws, size_t ws_size,
                              hipStream_t stream) {
    const float* x     = (const float*)d_in[0];
    const float* xproj = (const float*)d_in[4];
    const float* dtw   = (const float*)d_in[5];
    const float* dtb   = (const float*)d_in[6];
    const float* Alog  = (const float*)d_in[7];
    const float* Dp    = (const float*)d_in[8];
    const float* Kr    = (const float*)d_in[9];
    const float* Ki    = (const float*)d_in[10];
    const float* lng   = (const float*)d_in[11];
    const float* lnb   = (const float*)d_in[12];
    const float* ow    = (const float*)d_in[13];
    const float* ob    = (const float*)d_in[14];
    float* out = (float*)d_out;

    float* w = (float*)d_ws;
    float* means  = w; w += 256;
    float* stdev  = w; w += 256;
    short* twA    = (short*)w; w += 4096;
    float* xwT    = w; w += 20480;     // [li][d][80]
    float* dwT    = w; w += 2048;      // [li][r][128]
    float* ktr    = w; w += 65536;     // [li][x][o][i]
    float* kti    = w; w += 65536;
    float* enc    = w; w += 1048576;   // [r][d]
    float* xnR    = w; w += 1048576;   // [rp][d]
    float* deltaT = w; w += 1048576;   // [rp][d]
    float* BmR    = w; w += 262144;    // [rp][s]
    float* CmT    = w; w += 262144;    // [o][rp]
    float* gbuf   = w; w += 524288;    // [x2c][rp]
    short* ench   = (short*)w; w += 524288;    // bf16 [bc][4096]
    short* owh    = (short*)w; w += 393216;    // bf16 [t][4096]
    short* xfh    = (short*)w; w += 8388608;   // bf16 [m][rp][s]  (16,777,216 shorts)

    k_prep<<<3328, 256, 0, stream>>>(xproj, dtw, Kr, Ki, ow, x,
                                     twA, xwT, dwT, ktr, kti, owh, means, stdev);
    k_embed<<<4096, 256, 0, stream>>>(x, means, stdev, enc);
    for (int li = 0; li < 2; li++) {
        k_lnproj<<<8192, 128, 0, stream>>>(enc, xwT + li * 10240, dwT + li * 1024,
                                           dtb + li * 128, lng + li * 128, lnb + li * 128,
                                           xnR, deltaT, BmR, CmT);
        k_scandft<<<512, 64, 0, stream>>>(deltaT, xnR, BmR, Alog + li * 4096, twA, xfh);
        k_mix<<<1024, 256, 0, stream>>>(xfh, CmT, ktr + li * 32768, kti + li * 32768, gbuf);
        k_inv<<<8192, 128, 0, stream>>>(gbuf, Dp + li * 128, xnR, enc, ench,
                                        (li == 0) ? 1 : 0, (li == 1) ? 1 : 0);
    }
    k_head<<<192, 256, 0, stream>>>(ench, owh, ob, stdev, means, out);
}